// Round 12
// baseline (1483.721 us; speedup 1.0000x reference)
//
#include <hip/hip_runtime.h>
#include <hip/hip_bf16.h>

#define CC 64
#define HH 512
#define WWI 512
#define HWX (HH*WWI)
#define CHWX (CC*HWX)
#define EPSV 1e-5f

using bf16 = __hip_bfloat16;

__device__ __forceinline__ float b2f(bf16 v){ return __bfloat162float(v); }
__device__ __forceinline__ bf16 f2b(float v){ return __float2bfloat16(v); }
__device__ __forceinline__ float u2f(unsigned short u){
  unsigned int x = ((unsigned int)u) << 16;
  float f; __builtin_memcpy(&f, &x, 4); return f;
}
// pin a block-uniform float to an SGPR (keeps it out of the VGPR budget)
__device__ __forceinline__ float rfl(float v){
  int i; __builtin_memcpy(&i, &v, 4);
  i = __builtin_amdgcn_readfirstlane(i);
  float f; __builtin_memcpy(&f, &i, 4); return f;
}

template<bool MX>
__device__ __forceinline__ float opf(float a, float b){
  return MX ? fmaxf(a,b) : fminf(a,b);
}
template<bool MX>
__device__ __forceinline__ float4 opf4(float4 a, float4 b){
  return make_float4(opf<MX>(a.x,b.x), opf<MX>(a.y,b.y),
                     opf<MX>(a.z,b.z), opf<MX>(a.w,b.w));
}

// norm params from raw sums (block-uniform scalar math)
__device__ __forceinline__ void mk_norm(const float* s1, const float* s2, int c,
                                        float invN, float& m, float& r){
  m = s1[c] * invN;
  float v = fmaxf(s2[c] * invN - m * m, 0.f);
  r = rsqrtf(v + EPSV);
}

// 256-thread block. Reduce (v1,v2) across block, atomicAdd into s1,s2.
__device__ __forceinline__ void block_reduce_atomic(float v1, float v2,
                                                    float* s1, float* s2){
  #pragma unroll
  for (int o = 32; o > 0; o >>= 1){
    v1 += __shfl_down(v1, o);
    v2 += __shfl_down(v2, o);
  }
  __shared__ float a1[4], a2[4];
  int lane = threadIdx.x & 63, wid = threadIdx.x >> 6;
  if (lane == 0){ a1[wid] = v1; a2[wid] = v2; }
  __syncthreads();
  if (threadIdx.x == 0){
    atomicAdd(s1, a1[0]+a1[1]+a1[2]+a1[3]);
    atomicAdd(s2, a2[0]+a2[1]+a2[2]+a2[3]);
  }
}

// ======== fused morphology + depthwise conv + stats, float4 LDS passes ====
// CLOSING: maxpool2d then minpool2d (CLOS=true). OPENING: min then max.
// 32x64 tile (TH=64); streamed vertical passes; pass5 = 2 rows/thread.
// (R8 proven form.)
template<int P, bool CLOS>
__global__ __launch_bounds__(256) void morphdw(const float* __restrict__ in,
    const float* __restrict__ wgt, const float* __restrict__ bias,
    float* __restrict__ outF, float* __restrict__ s1, float* __restrict__ s2){
  constexpr int K   = 2*P+1;
  constexpr int TH  = 64;          // tile height
  constexpr int NIx = 32+6*P, NIy = TH+6*P;   // staged input
  constexpr int N1x = 32+4*P, N1y = TH+4*P;   // pool-1 region
  constexpr int N2x = 32+2*P, N2y = TH+2*P;   // morph region (dwconv input)
  constexpr int C1 = N1x/4, C2 = N2x/4;
  constexpr int G1y = N1y/4, G2y = N2y/4;     // streamed 4-row groups
  __shared__ __align__(16) float b0[NIy*NIx];
  __shared__ __align__(16) float b1[NIy*N1x];
  const int c = blockIdx.z;
  const int x0 = blockIdx.x*32, y0 = blockIdx.y*TH;
  const float* ip = in + (size_t)c*HWX;
  const int tid = threadIdx.x;
  // stage input, clamp-to-edge (exact for the first pool)
  for (int i = tid; i < NIy*NIx; i += 256){
    int r = i / NIx, cc = i - r*NIx;
    int gy = min(max(y0 - 3*P + r, 0), HH-1);
    int gx = min(max(x0 - 3*P + cc, 0), WWI-1);
    b0[i] = ip[gy*WWI+gx];
  }
  __syncthreads();
  // pass1: op1 horizontal, b0(NIy x NIx) -> b1(NIy x N1x)
  for (int i = tid; i < NIy*C1; i += 256){
    int r = i / C1, cg = i - r*C1;
    const float* p = &b0[r*NIx + 4*cg];
    float v[4+2*P];
    #pragma unroll
    for (int q = 0; q < (4+2*P)/4; ++q){
      float4 t = *(const float4*)(p + 4*q);
      v[4*q]=t.x; v[4*q+1]=t.y; v[4*q+2]=t.z; v[4*q+3]=t.w;
    }
    float cm = v[3];
    #pragma unroll
    for (int q = 4; q <= 2*P; ++q) cm = opf<CLOS>(cm, v[q]);
    float4 o;
    o.x = opf<CLOS>(opf<CLOS>(opf<CLOS>(cm, v[0]), v[1]), v[2]);
    o.y = opf<CLOS>(opf<CLOS>(opf<CLOS>(cm, v[1]), v[2]), v[2*P+1]);
    o.z = opf<CLOS>(opf<CLOS>(opf<CLOS>(cm, v[2]), v[2*P+1]), v[2*P+2]);
    o.w = opf<CLOS>(opf<CLOS>(opf<CLOS>(cm, v[2*P+1]), v[2*P+2]), v[2*P+3]);
    *(float4*)&b1[r*N1x + 4*cg] = o;
  }
  __syncthreads();
  // pass2: op1 vertical STREAMED (4 out rows/thread) + OOB -> op2-neutral
  for (int i = tid; i < G1y*C1; i += 256){
    int rg = i / C1, cg = i - rg*C1;
    const int R = 4*rg;
    float4 a0, a1, a2, a3;
    #pragma unroll
    for (int q = 0; q < 4+2*P; ++q){
      float4 v = *(const float4*)&b1[(R+q)*N1x + 4*cg];
      if (q == 0) a0 = v; else if (q <= 2*P)            a0 = opf4<CLOS>(a0, v);
      if (q == 1) a1 = v; else if (q > 1 && q <= 2*P+1) a1 = opf4<CLOS>(a1, v);
      if (q == 2) a2 = v; else if (q > 2 && q <= 2*P+2) a2 = opf4<CLOS>(a2, v);
      if (q == 3) a3 = v; else if (q > 3)               a3 = opf4<CLOS>(a3, v);
    }
    const float neut = CLOS ? 3.4e38f : -3.4e38f;
    int gx = x0 - 2*P + 4*cg;
    bool okx0 = (unsigned)(gx  ) < WWI, okx1 = (unsigned)(gx+1) < WWI;
    bool okx2 = (unsigned)(gx+2) < WWI, okx3 = (unsigned)(gx+3) < WWI;
    #pragma unroll
    for (int j = 0; j < 4; ++j){
      float4 m = (j==0)?a0:(j==1)?a1:(j==2)?a2:a3;
      int r = R + j;
      bool oky = (unsigned)(y0 - 2*P + r) < HH;
      m.x = (oky && okx0) ? m.x : neut;
      m.y = (oky && okx1) ? m.y : neut;
      m.z = (oky && okx2) ? m.z : neut;
      m.w = (oky && okx3) ? m.w : neut;
      *(float4*)&b0[r*N1x + 4*cg] = m;
    }
  }
  __syncthreads();
  // pass3: op2 horizontal, b0(N1y x N1x) -> b1(N1y x N2x)
  for (int i = tid; i < N1y*C2; i += 256){
    int r = i / C2, cg = i - r*C2;
    const float* p = &b0[r*N1x + 4*cg];
    float v[4+2*P];
    #pragma unroll
    for (int q = 0; q < (4+2*P)/4; ++q){
      float4 t = *(const float4*)(p + 4*q);
      v[4*q]=t.x; v[4*q+1]=t.y; v[4*q+2]=t.z; v[4*q+3]=t.w;
    }
    float cm = v[3];
    #pragma unroll
    for (int q = 4; q <= 2*P; ++q) cm = opf<!CLOS>(cm, v[q]);
    float4 o;
    o.x = opf<!CLOS>(opf<!CLOS>(opf<!CLOS>(cm, v[0]), v[1]), v[2]);
    o.y = opf<!CLOS>(opf<!CLOS>(opf<!CLOS>(cm, v[1]), v[2]), v[2*P+1]);
    o.z = opf<!CLOS>(opf<!CLOS>(opf<!CLOS>(cm, v[2]), v[2*P+1]), v[2*P+2]);
    o.w = opf<!CLOS>(opf<!CLOS>(opf<!CLOS>(cm, v[2*P+1]), v[2*P+2]), v[2*P+3]);
    *(float4*)&b1[r*N2x + 4*cg] = o;
  }
  __syncthreads();
  // pass4: op2 vertical STREAMED (4 out rows/thread) + OOB -> 0 (conv pad)
  for (int i = tid; i < G2y*C2; i += 256){
    int rg = i / C2, cg = i - rg*C2;
    const int R = 4*rg;
    float4 a0, a1, a2, a3;
    #pragma unroll
    for (int q = 0; q < 4+2*P; ++q){
      float4 v = *(const float4*)&b1[(R+q)*N2x + 4*cg];
      if (q == 0) a0 = v; else if (q <= 2*P)            a0 = opf4<!CLOS>(a0, v);
      if (q == 1) a1 = v; else if (q > 1 && q <= 2*P+1) a1 = opf4<!CLOS>(a1, v);
      if (q == 2) a2 = v; else if (q > 2 && q <= 2*P+2) a2 = opf4<!CLOS>(a2, v);
      if (q == 3) a3 = v; else if (q > 3)               a3 = opf4<!CLOS>(a3, v);
    }
    int gx = x0 - P + 4*cg;
    bool okx0 = (unsigned)(gx  ) < WWI, okx1 = (unsigned)(gx+1) < WWI;
    bool okx2 = (unsigned)(gx+2) < WWI, okx3 = (unsigned)(gx+3) < WWI;
    #pragma unroll
    for (int j = 0; j < 4; ++j){
      float4 m = (j==0)?a0:(j==1)?a1:(j==2)?a2:a3;
      int r = R + j;
      bool oky = (unsigned)(y0 - P + r) < HH;
      m.x = (oky && okx0) ? m.x : 0.f;
      m.y = (oky && okx1) ? m.y : 0.f;
      m.z = (oky && okx2) ? m.z : 0.f;
      m.w = (oky && okx3) ? m.w : 0.f;
      *(float4*)&b0[r*N2x + 4*cg] = m;
    }
  }
  __syncthreads();
  // pass5: dwconv KxK, thread = 2 rows x 4 cols, stream K+1 rows once
  const float* wp = wgt + c*K*K;
  const int cg = tid & 7, rg = tid >> 3;     // rg in [0,32)
  const int c0 = 4*cg, r0 = 2*rg;
  float bb = bias[c];
  float a0=bb, a1=bb, a2=bb, a3=bb;          // row r0
  float e0=bb, e1=bb, e2=bb, e3=bb;          // row r0+1
  #pragma unroll
  for (int q = 0; q <= K; ++q){
    float v[4+2*P];
    const float* p = &b0[(r0+q)*N2x + c0];
    #pragma unroll
    for (int t = 0; t < (4+2*P)/4; ++t){
      float4 f = *(const float4*)(p + 4*t);
      v[4*t]=f.x; v[4*t+1]=f.y; v[4*t+2]=f.z; v[4*t+3]=f.w;
    }
    if (q < K){                    // acc row r0: dy = q
      #pragma unroll
      for (int dx = 0; dx < K; ++dx){
        float w = wp[q*K+dx];
        a0 += w*v[dx]; a1 += w*v[dx+1]; a2 += w*v[dx+2]; a3 += w*v[dx+3];
      }
    }
    if (q >= 1){                   // acc row r0+1: dy = q-1
      #pragma unroll
      for (int dx = 0; dx < K; ++dx){
        float w = wp[(q-1)*K+dx];
        e0 += w*v[dx]; e1 += w*v[dx+1]; e2 += w*v[dx+2]; e3 += w*v[dx+3];
      }
    }
  }
  float* op = outF + (size_t)c*HWX;
  *(float4*)&op[(size_t)(y0+r0  )*WWI + x0 + c0] = make_float4(a0,a1,a2,a3);
  *(float4*)&op[(size_t)(y0+r0+1)*WWI + x0 + c0] = make_float4(e0,e1,e2,e3);
  block_reduce_atomic((a0+a1+a2+a3) + (e0+e1+e2+e3),
                      (a0*a0+a1*a1+a2*a2+a3*a3) + (e0*e0+e1*e1+e2*e2+e3*e3),
                      s1+c, s2+c);
}

// -------- stats of d = sgn*(relu(norm(A)) - x); grid-stride x4 ----------
__global__ __launch_bounds__(256) void diff_stats4(const float4* __restrict__ A,
    const float4* __restrict__ x,
    const float* __restrict__ s1i, const float* __restrict__ s2i, float invN,
    float sgn, float* __restrict__ s1, float* __restrict__ s2){
  int c = blockIdx.z;
  float m, r;
  mk_norm(s1i, s2i, c, invN, m, r);
  size_t base = (size_t)c * (HWX/4) + blockIdx.x * 1024 + threadIdx.x;
  float sv = 0.f, sq = 0.f;
  #pragma unroll
  for (int k = 0; k < 4; ++k){
    size_t i = base + k*256;
    float4 f = A[i], xv = x[i];
    float d0 = sgn * (fmaxf((f.x - m) * r, 0.f) - xv.x);
    float d1 = sgn * (fmaxf((f.y - m) * r, 0.f) - xv.y);
    float d2 = sgn * (fmaxf((f.z - m) * r, 0.f) - xv.z);
    float d3 = sgn * (fmaxf((f.w - m) * r, 0.f) - xv.w);
    sv += d0+d1+d2+d3;
    sq += d0*d0+d1*d1+d2*d2+d3*d3;
  }
  block_reduce_atomic(sv, sq, s1 + c, s2 + c);
}

// ======== 3x3 dwconv of norm(d); 32x64 tile, 2 rows/thread streamed ======
// (R11 form, neutral-to-positive, VGPR-safe.)
__global__ __launch_bounds__(256) void conv3_acc(const float* __restrict__ A,
    const float* __restrict__ x,
    const float* __restrict__ s1A, const float* __restrict__ s2A,
    const float* __restrict__ s1D, const float* __restrict__ s2D, float invN,
    float sgn, const float* __restrict__ w3, const float* __restrict__ b3,
    float* __restrict__ comb, int first){
  __shared__ __align__(16) float S[66*36];   // 9504 B
  const int c = blockIdx.z;
  const int x0 = blockIdx.x*32, y0 = blockIdx.y*64;
  float mA_, rA_, mD_, rD_;
  mk_norm(s1A, s2A, c, invN, mA_, rA_);
  mk_norm(s1D, s2D, c, invN, mD_, rD_);
  const float mA = rfl(mA_), rA = rfl(rA_), mD = rfl(mD_), rD = rfl(rD_);
  const float* ap = A + (size_t)c*HWX;
  const float* xp = x + (size_t)c*HWX;
  const int tid = threadIdx.x;
  // 66*34 = 2244 = 8*256 + 196 -> 9 chunks, unrolled for load overlap
  #pragma unroll
  for (int k = 0; k < 9; ++k){
    const int i = tid + k*256;
    const bool act = (k < 8) || (tid < 2244 - 2048);
    const int rr = i / 34, cc = i - rr*34;
    const int gy = y0 - 1 + rr, gx = x0 - 1 + cc;
    const bool ok = act && ((unsigned)gy < HH) && ((unsigned)gx < WWI);
    const int ad = min(max(gy,0),HH-1)*WWI + min(max(gx,0),WWI-1);
    float av = act ? ap[ad] : 0.f;
    float xv = act ? xp[ad] : 0.f;
    float dval = sgn * (fmaxf((av - mA) * rA, 0.f) - xv);
    if (act) S[rr*36+cc] = ok ? (dval - mD) * rD : 0.f;
  }
  __syncthreads();
  const int cg = tid & 7, rg = tid >> 3;   // rg in [0,32)
  const int c0 = 4*cg, r0 = 2*rg;          // output rows r0, r0+1
  const float* wp = w3 + c*9;
  float bb = b3[c];
  float a0[4] = {bb,bb,bb,bb};
  float a1[4] = {bb,bb,bb,bb};
  #pragma unroll
  for (int q = 0; q < 4; ++q){
    const float* p = &S[(r0+q)*36 + c0];
    float4 t0 = *(const float4*)p;
    float4 t1 = *(const float4*)(p+4);
    float v[6] = {t0.x,t0.y,t0.z,t0.w,t1.x,t1.y};
    if (q < 3){                    // out row r0: dy = q
      #pragma unroll
      for (int dx = 0; dx < 3; ++dx){
        float w = wp[q*3+dx];
        #pragma unroll
        for (int j = 0; j < 4; ++j) a0[j] += w * v[j+dx];
      }
    }
    if (q >= 1){                   // out row r0+1: dy = q-1
      #pragma unroll
      for (int dx = 0; dx < 3; ++dx){
        float w = wp[(q-1)*3+dx];
        #pragma unroll
        for (int j = 0; j < 4; ++j) a1[j] += w * v[j+dx];
      }
    }
  }
  float* cb = comb + (size_t)c*HWX;
  float4* cp0 = (float4*)&cb[(size_t)(y0+r0  )*WWI + x0 + c0];
  float4* cp1 = (float4*)&cb[(size_t)(y0+r0+1)*WWI + x0 + c0];
  float4 o0 = make_float4(a0[0],a0[1],a0[2],a0[3]);
  float4 o1 = make_float4(a1[0],a1[1],a1[2],a1[3]);
  if (!first){
    float4 p0 = *cp0, p1 = *cp1;
    o0.x += p0.x; o0.y += p0.y; o0.z += p0.z; o0.w += p0.w;
    o1.x += p1.x; o1.y += p1.y; o1.z += p1.z; o1.w += p1.w;
  }
  *cp0 = o0;
  *cp1 = o1;
}

// ======== Conv3d #1: 4 d-planes per block, 6 staged planes, row x 4col ====
// Staging: chunk-outer / plane-inner (R10 proven form).
__global__ __launch_bounds__(256) void conv3d1(const float* __restrict__ comb,
    const float* __restrict__ wt, const float* __restrict__ bt,
    bf16* __restrict__ T, float* __restrict__ s1, float* __restrict__ s2){
  __shared__ __align__(16) float S[6][34*36];
  __shared__ float red[4][6];
  const int d0 = blockIdx.z * 4;
  const int x0 = blockIdx.x*32, y0 = blockIdx.y*32;
  const int tid = threadIdx.x;
  #pragma unroll
  for (int k = 0; k < 5; ++k){
    const int i = tid + k*256;
    const bool act = (k < 4) || (tid < 1156 - 1024);
    const int rr = i / 34, cc = i - rr*34;
    const int gy = y0 - 1 + rr, gx = x0 - 1 + cc;
    const bool okxy = act && ((unsigned)gy < HH) && ((unsigned)gx < WWI);
    const int ad = min(max(gy,0),HH-1)*WWI + min(max(gx,0),WWI-1);
    float v[6];
    #pragma unroll
    for (int j = 0; j < 6; ++j){
      const int dz = d0 - 1 + j;
      const float* ip = comb + (size_t)min(max(dz,0),CC-1) * HWX;
      v[j] = act ? ip[ad] : 0.f;
    }
    #pragma unroll
    for (int j = 0; j < 6; ++j){
      const bool ok = okxy && ((unsigned)(d0-1+j) < CC);
      if (act) S[j][rr*36+cc] = ok ? v[j] : 0.f;
    }
  }
  __syncthreads();
  const int cg = tid & 7, row = tid >> 3;
  const int c0 = 4*cg;
  const int lane = tid & 63, wid = tid >> 6;
  for (int dl = 0; dl < 4; ++dl){
    const int d = d0 + dl;
    float acc[3][4];
    #pragma unroll
    for (int oc = 0; oc < 3; ++oc){
      float b = bt[oc];
      #pragma unroll
      for (int j = 0; j < 4; ++j) acc[oc][j] = b;
    }
    #pragma unroll
    for (int dd = 0; dd < 3; ++dd){
      const float* sp = S[dl+dd];
      #pragma unroll
      for (int dy = 0; dy < 3; ++dy){
        const float* p = &sp[(row+dy)*36 + c0];
        float4 t0 = *(const float4*)p;
        float4 t1 = *(const float4*)(p+4);
        float v[6] = {t0.x,t0.y,t0.z,t0.w,t1.x,t1.y};
        #pragma unroll
        for (int dx = 0; dx < 3; ++dx){
          #pragma unroll
          for (int oc = 0; oc < 3; ++oc){
            float w = wt[oc*27 + dd*9 + dy*3 + dx];
            #pragma unroll
            for (int j = 0; j < 4; ++j) acc[oc][j] += w * v[j+dx];
          }
        }
      }
    }
    float vals[6] = {0,0,0,0,0,0};
    #pragma unroll
    for (int oc = 0; oc < 3; ++oc){
      bf16* tp = T + (size_t)(oc*CC + d)*HWX;
      union { ushort4 u; bf16 h[4]; } pk;
      #pragma unroll
      for (int j = 0; j < 4; ++j){
        pk.h[j] = f2b(acc[oc][j]);
        float av = b2f(pk.h[j]);          // stats match stored bf16
        vals[2*oc]   += av;
        vals[2*oc+1] += av*av;
      }
      *(ushort4*)&tp[(size_t)(y0+row)*WWI + x0 + c0] = pk.u;
    }
    #pragma unroll
    for (int o = 32; o > 0; o >>= 1)
      #pragma unroll
      for (int k = 0; k < 6; ++k) vals[k] += __shfl_down(vals[k], o);
    __syncthreads();                      // protect red[] from prev iter
    if (lane == 0)
      #pragma unroll
      for (int k = 0; k < 6; ++k) red[wid][k] = vals[k];
    __syncthreads();
    if (tid == 0){
      #pragma unroll
      for (int oc = 0; oc < 3; ++oc){
        atomicAdd(s1 + oc*CC + d, red[0][2*oc]  +red[1][2*oc]  +red[2][2*oc]  +red[3][2*oc]);
        atomicAdd(s2 + oc*CC + d, red[0][2*oc+1]+red[1][2*oc+1]+red[2][2*oc+1]+red[3][2*oc+1]);
      }
    }
  }
}

// ======== Conv3d #2: DPB=4, 18 relu-norm bf16 planes, pitch 36 ==========
// Compute: R10-proven single-acc dl-loop (dl 0..3) — all dual-acc variants
// blew VGPR (R3/R4/R11: 100-104 -> occupancy cliff). Staging/fetch
// amortization instead: 18 staged planes serve 4 outputs (4.5 planes/out
// vs DPB=2's 6) -> staging work and T re-fetch -25%. LDS 44064 B ->
// 3 blocks/CU (occ cap 37.5%; R10 showed occupancy isn't binding here).
// Per-output FP order (i3, dd, dy, dx) unchanged -> bit-exact.
__global__ __launch_bounds__(256) void conv3d2_final(const bf16* __restrict__ T,
    const float* __restrict__ s1i, const float* __restrict__ s2i, float invN,
    const float* __restrict__ wt2, const float* __restrict__ bt2,
    const float* __restrict__ x, float* __restrict__ out){
  __shared__ __align__(16) bf16 S16[18][34*36];   // 44064 B
  const int d0 = blockIdx.z * 4;
  const int x0 = blockIdx.x*32, y0 = blockIdx.y*32;
  const int tid = threadIdx.x;

  // uniform per-plane params (SGPR-pinned)
  float ms[18], rs[18];
  #pragma unroll
  for (int p = 0; p < 18; ++p){
    const int i3 = p / 6, j = p - i3*6;
    const int dz = d0 - 1 + j;
    const int ch = i3*CC + min(max(dz,0),CC-1);
    float m, r; mk_norm(s1i, s2i, ch, invN, m, r);
    ms[p] = rfl(m); rs[p] = rfl(r);
  }

  // stage 18 planes in 3 chunks of 18 independent loads (34 x 18 pairs)
  #pragma unroll
  for (int k = 0; k < 3; ++k){
    const int i = tid + k*256;              // index in 34x18 element grid
    const bool act = (k < 2) || (tid < 612 - 512);
    const int rr = i / 18, s = i - rr*18;
    const int gy = y0 - 1 + rr;
    const int gx = x0 - 2 + 2*s;            // even, cols 0..35
    const int ay = min(max(gy,0),HH-1);
    const int ax = min(max(gx,0),WWI-2);    // even, ushort2-safe
    const int aoff = (ay<<9) + ax;
    unsigned int tv[18];
    #pragma unroll
    for (int p = 0; p < 18; ++p){
      const int i3 = p / 6, j = p - i3*6;
      const int ch = i3*CC + min(max(d0-1+j,0),CC-1);
      const bf16* tp = T + (size_t)ch*HWX;
      ushort2 t = act ? *(const ushort2*)(tp + aoff) : make_ushort2(0,0);
      tv[p] = (((unsigned)t.y) << 16) | (unsigned)t.x;
    }
    const bool oky  = act && ((unsigned)gy < HH);
    const bool okx0 = (unsigned)gx     < WWI;
    const bool okx1 = (unsigned)(gx+1) < WWI;
    #pragma unroll
    for (int p = 0; p < 18; ++p){
      const int i3 = p / 6, j = p - i3*6;
      const bool zok = (unsigned)(d0-1+j) < CC;
      const bool bok = oky && zok;
      unsigned lo = tv[p] << 16, hi = tv[p] & 0xffff0000u;
      float f0, f1;
      __builtin_memcpy(&f0, &lo, 4); __builtin_memcpy(&f1, &hi, 4);
      float u0 = (bok && okx0) ? fmaxf((f0 - ms[p]) * rs[p], 0.f) : 0.f;
      float u1 = (bok && okx1) ? fmaxf((f1 - ms[p]) * rs[p], 0.f) : 0.f;
      union { ushort2 u; bf16 h[2]; } pk;
      pk.h[0] = f2b(u0); pk.h[1] = f2b(u1);
      if (act) *(ushort2*)(S16[p] + rr*36 + 2*s) = pk.u;
    }
  }
  __syncthreads();

  const int cg = tid & 7, row = tid >> 3;
  const int c0 = 4*cg;
  for (int dl = 0; dl < 4; ++dl){
    const int d = d0 + dl;
    const float bb = bt2[0];
    float acc[4] = {bb,bb,bb,bb};
    #pragma unroll
    for (int i3 = 0; i3 < 3; ++i3){
      #pragma unroll
      for (int dd = 0; dd < 3; ++dd){
        const bf16* sp = S16[i3*6 + dl + dd];
        #pragma unroll
        for (int dy = 0; dy < 3; ++dy){
          // needed cols (global x0+c0-1 .. x0+c0+4) = LDS cols c0+1 .. c0+6
          const bf16* p = &sp[(row+dy)*36 + c0];
          ushort4 lo = *(const ushort4*)p;
          ushort4 hi = *(const ushort4*)(p+4);
          float v[6] = {u2f(lo.y),u2f(lo.z),u2f(lo.w),
                        u2f(hi.x),u2f(hi.y),u2f(hi.z)};
          #pragma unroll
          for (int dx = 0; dx < 3; ++dx){
            float w = wt2[(i3*3+dd)*9 + dy*3 + dx];
            #pragma unroll
            for (int q = 0; q < 4; ++q) acc[q] += w * v[q+dx];
          }
        }
      }
    }
    size_t gi = (size_t)d*HWX + (size_t)(y0+row)*WWI + x0 + c0;
    float4 xv = *(const float4*)&x[gi];
    float4 o;
    o.x = fmaxf(xv.x / (1.f + __expf(-acc[0])), 0.f);
    o.y = fmaxf(xv.y / (1.f + __expf(-acc[1])), 0.f);
    o.z = fmaxf(xv.z / (1.f + __expf(-acc[2])), 0.f);
    o.w = fmaxf(xv.w / (1.f + __expf(-acc[3])), 0.f);
    *(float4*)&out[gi] = o;
  }
}

extern "C" void kernel_launch(void* const* d_in, const int* in_sizes, int n_in,
                              void* d_out, int out_size, void* d_ws, size_t ws_size,
                              hipStream_t stream){
  const float* x     = (const float*)d_in[0];
  const float* w_wt5 = (const float*)d_in[1];
  const float* b_wt5 = (const float*)d_in[2];
  const float* w_wt9 = (const float*)d_in[3];
  const float* b_wt9 = (const float*)d_in[4];
  const float* w_bt5 = (const float*)d_in[5];
  const float* b_bt5 = (const float*)d_in[6];
  const float* w_bt9 = (const float*)d_in[7];
  const float* b_bt9 = (const float*)d_in[8];
  const float* w_wn  = (const float*)d_in[9];
  const float* b_wn  = (const float*)d_in[10];
  const float* w_t1  = (const float*)d_in[11];
  const float* b_t1  = (const float*)d_in[12];
  const float* w_t2  = (const float*)d_in[13];
  const float* b_t2  = (const float*)d_in[14];
  float* out = (float*)d_out;

  // ---- workspace layout ----
  char* ws = (char*)d_ws;
  float* A    = (float*)ws;                        // branch dwconv out
  float* comb = (float*)(ws + 2*(size_t)CHWX*4);   // accumulator
  bf16*  T    = (bf16*)ws;                         // 3*CHWX bf16 overlay
  float* stats = comb + (size_t)CHWX;
  float* s1 = stats;        // 704
  float* s2 = stats + 704;  // 704

  hipMemsetAsync(s1, 0, 1408 * sizeof(float), stream);

  dim3 blk(256);
  dim3 gridMor(WWI/32, HH/64, CC);          // (16,8,64) morphdw 32x64 tile
  dim3 gridC3(WWI/32, HH/64, CC);           // (16,8,64) conv3_acc 32x64 tile
  dim3 gridM4(WWI/32, HH/32, CC/4);         // (16,16,16)
  dim3 gridT4(WWI/32, HH/32, CC/4);         // (16,16,16) conv3d2 DPB=4
  dim3 gridD(64, 1, CC);                    // diff grid-stride x4
  float invHW = 1.f / (float)HWX;

  int first = 1;
  for (int ki = 0; ki < 2; ++ki){
    for (int br = 0; br < 2; ++br){
      int st = (ki * 2 + br) * 2;
      if (ki == 0){
        if (br == 0) morphdw<2, true ><<<gridMor, blk, 0, stream>>>(x, w_wt5, b_wt5, A, s1+st*64, s2+st*64);
        else         morphdw<2, false><<<gridMor, blk, 0, stream>>>(x, w_bt5, b_bt5, A, s1+st*64, s2+st*64);
      } else {
        if (br == 0) morphdw<4, true ><<<gridMor, blk, 0, stream>>>(x, w_wt9, b_wt9, A, s1+st*64, s2+st*64);
        else         morphdw<4, false><<<gridMor, blk, 0, stream>>>(x, w_bt9, b_bt9, A, s1+st*64, s2+st*64);
      }
      float sgn = (br == 0) ? -1.f : 1.f;   // WTHAM: x - wth ; BTHAM: bth - x
      diff_stats4<<<gridD, blk, 0, stream>>>((const float4*)A, (const float4*)x,
                                             s1 + st*64, s2 + st*64, invHW, sgn,
                                             s1 + (st+1)*64, s2 + (st+1)*64);
      conv3_acc<<<gridC3, blk, 0, stream>>>(A, x, s1 + st*64, s2 + st*64,
                                            s1 + (st+1)*64, s2 + (st+1)*64, invHW,
                                            sgn, w_wn, b_wn, comb, first);
      first = 0;
    }
  }

  // ---- temporal cross ----
  conv3d1<<<gridM4, blk, 0, stream>>>(comb, w_t1, b_t1, T, s1 + 512, s2 + 512);
  conv3d2_final<<<gridT4, blk, 0, stream>>>(T, s1 + 512, s2 + 512, invHW,
                                            w_t2, b_t2, x, out);
}

// Round 13
// 1455.297 us; speedup vs baseline: 1.0195x; 1.0195x over previous
//
#include <hip/hip_runtime.h>
#include <hip/hip_bf16.h>

#define CC 64
#define HH 512
#define WWI 512
#define HWX (HH*WWI)
#define CHWX (CC*HWX)
#define EPSV 1e-5f

using bf16 = __hip_bfloat16;

__device__ __forceinline__ float b2f(bf16 v){ return __bfloat162float(v); }
__device__ __forceinline__ bf16 f2b(float v){ return __float2bfloat16(v); }
__device__ __forceinline__ float u2f(unsigned short u){
  unsigned int x = ((unsigned int)u) << 16;
  float f; __builtin_memcpy(&f, &x, 4); return f;
}
// pin a block-uniform float to an SGPR (keeps it out of the VGPR budget)
__device__ __forceinline__ float rfl(float v){
  int i; __builtin_memcpy(&i, &v, 4);
  i = __builtin_amdgcn_readfirstlane(i);
  float f; __builtin_memcpy(&f, &i, 4); return f;
}

template<bool MX>
__device__ __forceinline__ float opf(float a, float b){
  return MX ? fmaxf(a,b) : fminf(a,b);
}
template<bool MX>
__device__ __forceinline__ float4 opf4(float4 a, float4 b){
  return make_float4(opf<MX>(a.x,b.x), opf<MX>(a.y,b.y),
                     opf<MX>(a.z,b.z), opf<MX>(a.w,b.w));
}

// norm params from raw sums (block-uniform scalar math)
__device__ __forceinline__ void mk_norm(const float* s1, const float* s2, int c,
                                        float invN, float& m, float& r){
  m = s1[c] * invN;
  float v = fmaxf(s2[c] * invN - m * m, 0.f);
  r = rsqrtf(v + EPSV);
}

// 256-thread block. Reduce (v1,v2) across block, atomicAdd into s1,s2.
__device__ __forceinline__ void block_reduce_atomic(float v1, float v2,
                                                    float* s1, float* s2){
  #pragma unroll
  for (int o = 32; o > 0; o >>= 1){
    v1 += __shfl_down(v1, o);
    v2 += __shfl_down(v2, o);
  }
  __shared__ float a1[4], a2[4];
  int lane = threadIdx.x & 63, wid = threadIdx.x >> 6;
  if (lane == 0){ a1[wid] = v1; a2[wid] = v2; }
  __syncthreads();
  if (threadIdx.x == 0){
    atomicAdd(s1, a1[0]+a1[1]+a1[2]+a1[3]);
    atomicAdd(s2, a2[0]+a2[1]+a2[2]+a2[3]);
  }
}

// ======== fused morphology + depthwise conv + stats, float4 LDS passes ====
// CLOSING: maxpool2d then minpool2d (CLOS=true). OPENING: min then max.
// 32x64 tile (TH=64); streamed vertical passes; pass5 = 2 rows/thread.
// (R8 proven form.)
template<int P, bool CLOS>
__global__ __launch_bounds__(256) void morphdw(const float* __restrict__ in,
    const float* __restrict__ wgt, const float* __restrict__ bias,
    float* __restrict__ outF, float* __restrict__ s1, float* __restrict__ s2){
  constexpr int K   = 2*P+1;
  constexpr int TH  = 64;          // tile height
  constexpr int NIx = 32+6*P, NIy = TH+6*P;   // staged input
  constexpr int N1x = 32+4*P, N1y = TH+4*P;   // pool-1 region
  constexpr int N2x = 32+2*P, N2y = TH+2*P;   // morph region (dwconv input)
  constexpr int C1 = N1x/4, C2 = N2x/4;
  constexpr int G1y = N1y/4, G2y = N2y/4;     // streamed 4-row groups
  __shared__ __align__(16) float b0[NIy*NIx];
  __shared__ __align__(16) float b1[NIy*N1x];
  const int c = blockIdx.z;
  const int x0 = blockIdx.x*32, y0 = blockIdx.y*TH;
  const float* ip = in + (size_t)c*HWX;
  const int tid = threadIdx.x;
  // stage input, clamp-to-edge (exact for the first pool)
  for (int i = tid; i < NIy*NIx; i += 256){
    int r = i / NIx, cc = i - r*NIx;
    int gy = min(max(y0 - 3*P + r, 0), HH-1);
    int gx = min(max(x0 - 3*P + cc, 0), WWI-1);
    b0[i] = ip[gy*WWI+gx];
  }
  __syncthreads();
  // pass1: op1 horizontal, b0(NIy x NIx) -> b1(NIy x N1x)
  for (int i = tid; i < NIy*C1; i += 256){
    int r = i / C1, cg = i - r*C1;
    const float* p = &b0[r*NIx + 4*cg];
    float v[4+2*P];
    #pragma unroll
    for (int q = 0; q < (4+2*P)/4; ++q){
      float4 t = *(const float4*)(p + 4*q);
      v[4*q]=t.x; v[4*q+1]=t.y; v[4*q+2]=t.z; v[4*q+3]=t.w;
    }
    float cm = v[3];
    #pragma unroll
    for (int q = 4; q <= 2*P; ++q) cm = opf<CLOS>(cm, v[q]);
    float4 o;
    o.x = opf<CLOS>(opf<CLOS>(opf<CLOS>(cm, v[0]), v[1]), v[2]);
    o.y = opf<CLOS>(opf<CLOS>(opf<CLOS>(cm, v[1]), v[2]), v[2*P+1]);
    o.z = opf<CLOS>(opf<CLOS>(opf<CLOS>(cm, v[2]), v[2*P+1]), v[2*P+2]);
    o.w = opf<CLOS>(opf<CLOS>(opf<CLOS>(cm, v[2*P+1]), v[2*P+2]), v[2*P+3]);
    *(float4*)&b1[r*N1x + 4*cg] = o;
  }
  __syncthreads();
  // pass2: op1 vertical STREAMED (4 out rows/thread) + OOB -> op2-neutral
  for (int i = tid; i < G1y*C1; i += 256){
    int rg = i / C1, cg = i - rg*C1;
    const int R = 4*rg;
    float4 a0, a1, a2, a3;
    #pragma unroll
    for (int q = 0; q < 4+2*P; ++q){
      float4 v = *(const float4*)&b1[(R+q)*N1x + 4*cg];
      if (q == 0) a0 = v; else if (q <= 2*P)            a0 = opf4<CLOS>(a0, v);
      if (q == 1) a1 = v; else if (q > 1 && q <= 2*P+1) a1 = opf4<CLOS>(a1, v);
      if (q == 2) a2 = v; else if (q > 2 && q <= 2*P+2) a2 = opf4<CLOS>(a2, v);
      if (q == 3) a3 = v; else if (q > 3)               a3 = opf4<CLOS>(a3, v);
    }
    const float neut = CLOS ? 3.4e38f : -3.4e38f;
    int gx = x0 - 2*P + 4*cg;
    bool okx0 = (unsigned)(gx  ) < WWI, okx1 = (unsigned)(gx+1) < WWI;
    bool okx2 = (unsigned)(gx+2) < WWI, okx3 = (unsigned)(gx+3) < WWI;
    #pragma unroll
    for (int j = 0; j < 4; ++j){
      float4 m = (j==0)?a0:(j==1)?a1:(j==2)?a2:a3;
      int r = R + j;
      bool oky = (unsigned)(y0 - 2*P + r) < HH;
      m.x = (oky && okx0) ? m.x : neut;
      m.y = (oky && okx1) ? m.y : neut;
      m.z = (oky && okx2) ? m.z : neut;
      m.w = (oky && okx3) ? m.w : neut;
      *(float4*)&b0[r*N1x + 4*cg] = m;
    }
  }
  __syncthreads();
  // pass3: op2 horizontal, b0(N1y x N1x) -> b1(N1y x N2x)
  for (int i = tid; i < N1y*C2; i += 256){
    int r = i / C2, cg = i - r*C2;
    const float* p = &b0[r*N1x + 4*cg];
    float v[4+2*P];
    #pragma unroll
    for (int q = 0; q < (4+2*P)/4; ++q){
      float4 t = *(const float4*)(p + 4*q);
      v[4*q]=t.x; v[4*q+1]=t.y; v[4*q+2]=t.z; v[4*q+3]=t.w;
    }
    float cm = v[3];
    #pragma unroll
    for (int q = 4; q <= 2*P; ++q) cm = opf<!CLOS>(cm, v[q]);
    float4 o;
    o.x = opf<!CLOS>(opf<!CLOS>(opf<!CLOS>(cm, v[0]), v[1]), v[2]);
    o.y = opf<!CLOS>(opf<!CLOS>(opf<!CLOS>(cm, v[1]), v[2]), v[2*P+1]);
    o.z = opf<!CLOS>(opf<!CLOS>(opf<!CLOS>(cm, v[2]), v[2*P+1]), v[2*P+2]);
    o.w = opf<!CLOS>(opf<!CLOS>(opf<!CLOS>(cm, v[2*P+1]), v[2*P+2]), v[2*P+3]);
    *(float4*)&b1[r*N2x + 4*cg] = o;
  }
  __syncthreads();
  // pass4: op2 vertical STREAMED (4 out rows/thread) + OOB -> 0 (conv pad)
  for (int i = tid; i < G2y*C2; i += 256){
    int rg = i / C2, cg = i - rg*C2;
    const int R = 4*rg;
    float4 a0, a1, a2, a3;
    #pragma unroll
    for (int q = 0; q < 4+2*P; ++q){
      float4 v = *(const float4*)&b1[(R+q)*N2x + 4*cg];
      if (q == 0) a0 = v; else if (q <= 2*P)            a0 = opf4<!CLOS>(a0, v);
      if (q == 1) a1 = v; else if (q > 1 && q <= 2*P+1) a1 = opf4<!CLOS>(a1, v);
      if (q == 2) a2 = v; else if (q > 2 && q <= 2*P+2) a2 = opf4<!CLOS>(a2, v);
      if (q == 3) a3 = v; else if (q > 3)               a3 = opf4<!CLOS>(a3, v);
    }
    int gx = x0 - P + 4*cg;
    bool okx0 = (unsigned)(gx  ) < WWI, okx1 = (unsigned)(gx+1) < WWI;
    bool okx2 = (unsigned)(gx+2) < WWI, okx3 = (unsigned)(gx+3) < WWI;
    #pragma unroll
    for (int j = 0; j < 4; ++j){
      float4 m = (j==0)?a0:(j==1)?a1:(j==2)?a2:a3;
      int r = R + j;
      bool oky = (unsigned)(y0 - P + r) < HH;
      m.x = (oky && okx0) ? m.x : 0.f;
      m.y = (oky && okx1) ? m.y : 0.f;
      m.z = (oky && okx2) ? m.z : 0.f;
      m.w = (oky && okx3) ? m.w : 0.f;
      *(float4*)&b0[r*N2x + 4*cg] = m;
    }
  }
  __syncthreads();
  // pass5: dwconv KxK, thread = 2 rows x 4 cols, stream K+1 rows once
  const float* wp = wgt + c*K*K;
  const int cg = tid & 7, rg = tid >> 3;     // rg in [0,32)
  const int c0 = 4*cg, r0 = 2*rg;
  float bb = bias[c];
  float a0=bb, a1=bb, a2=bb, a3=bb;          // row r0
  float e0=bb, e1=bb, e2=bb, e3=bb;          // row r0+1
  #pragma unroll
  for (int q = 0; q <= K; ++q){
    float v[4+2*P];
    const float* p = &b0[(r0+q)*N2x + c0];
    #pragma unroll
    for (int t = 0; t < (4+2*P)/4; ++t){
      float4 f = *(const float4*)(p + 4*t);
      v[4*t]=f.x; v[4*t+1]=f.y; v[4*t+2]=f.z; v[4*t+3]=f.w;
    }
    if (q < K){                    // acc row r0: dy = q
      #pragma unroll
      for (int dx = 0; dx < K; ++dx){
        float w = wp[q*K+dx];
        a0 += w*v[dx]; a1 += w*v[dx+1]; a2 += w*v[dx+2]; a3 += w*v[dx+3];
      }
    }
    if (q >= 1){                   // acc row r0+1: dy = q-1
      #pragma unroll
      for (int dx = 0; dx < K; ++dx){
        float w = wp[(q-1)*K+dx];
        e0 += w*v[dx]; e1 += w*v[dx+1]; e2 += w*v[dx+2]; e3 += w*v[dx+3];
      }
    }
  }
  float* op = outF + (size_t)c*HWX;
  *(float4*)&op[(size_t)(y0+r0  )*WWI + x0 + c0] = make_float4(a0,a1,a2,a3);
  *(float4*)&op[(size_t)(y0+r0+1)*WWI + x0 + c0] = make_float4(e0,e1,e2,e3);
  block_reduce_atomic((a0+a1+a2+a3) + (e0+e1+e2+e3),
                      (a0*a0+a1*a1+a2*a2+a3*a3) + (e0*e0+e1*e1+e2*e2+e3*e3),
                      s1+c, s2+c);
}

// -------- stats of d = sgn*(relu(norm(A)) - x); grid-stride x4 ----------
__global__ __launch_bounds__(256) void diff_stats4(const float4* __restrict__ A,
    const float4* __restrict__ x,
    const float* __restrict__ s1i, const float* __restrict__ s2i, float invN,
    float sgn, float* __restrict__ s1, float* __restrict__ s2){
  int c = blockIdx.z;
  float m, r;
  mk_norm(s1i, s2i, c, invN, m, r);
  size_t base = (size_t)c * (HWX/4) + blockIdx.x * 1024 + threadIdx.x;
  float sv = 0.f, sq = 0.f;
  #pragma unroll
  for (int k = 0; k < 4; ++k){
    size_t i = base + k*256;
    float4 f = A[i], xv = x[i];
    float d0 = sgn * (fmaxf((f.x - m) * r, 0.f) - xv.x);
    float d1 = sgn * (fmaxf((f.y - m) * r, 0.f) - xv.y);
    float d2 = sgn * (fmaxf((f.z - m) * r, 0.f) - xv.z);
    float d3 = sgn * (fmaxf((f.w - m) * r, 0.f) - xv.w);
    sv += d0+d1+d2+d3;
    sq += d0*d0+d1*d1+d2*d2+d3*d3;
  }
  block_reduce_atomic(sv, sq, s1 + c, s2 + c);
}

// ======== 3x3 dwconv of norm(d); 32x64 tile, 2 rows/thread streamed ======
// (R11 form, neutral-to-positive, VGPR-safe.)
__global__ __launch_bounds__(256) void conv3_acc(const float* __restrict__ A,
    const float* __restrict__ x,
    const float* __restrict__ s1A, const float* __restrict__ s2A,
    const float* __restrict__ s1D, const float* __restrict__ s2D, float invN,
    float sgn, const float* __restrict__ w3, const float* __restrict__ b3,
    float* __restrict__ comb, int first){
  __shared__ __align__(16) float S[66*36];   // 9504 B
  const int c = blockIdx.z;
  const int x0 = blockIdx.x*32, y0 = blockIdx.y*64;
  float mA_, rA_, mD_, rD_;
  mk_norm(s1A, s2A, c, invN, mA_, rA_);
  mk_norm(s1D, s2D, c, invN, mD_, rD_);
  const float mA = rfl(mA_), rA = rfl(rA_), mD = rfl(mD_), rD = rfl(rD_);
  const float* ap = A + (size_t)c*HWX;
  const float* xp = x + (size_t)c*HWX;
  const int tid = threadIdx.x;
  // 66*34 = 2244 = 8*256 + 196 -> 9 chunks, unrolled for load overlap
  #pragma unroll
  for (int k = 0; k < 9; ++k){
    const int i = tid + k*256;
    const bool act = (k < 8) || (tid < 2244 - 2048);
    const int rr = i / 34, cc = i - rr*34;
    const int gy = y0 - 1 + rr, gx = x0 - 1 + cc;
    const bool ok = act && ((unsigned)gy < HH) && ((unsigned)gx < WWI);
    const int ad = min(max(gy,0),HH-1)*WWI + min(max(gx,0),WWI-1);
    float av = act ? ap[ad] : 0.f;
    float xv = act ? xp[ad] : 0.f;
    float dval = sgn * (fmaxf((av - mA) * rA, 0.f) - xv);
    if (act) S[rr*36+cc] = ok ? (dval - mD) * rD : 0.f;
  }
  __syncthreads();
  const int cg = tid & 7, rg = tid >> 3;   // rg in [0,32)
  const int c0 = 4*cg, r0 = 2*rg;          // output rows r0, r0+1
  const float* wp = w3 + c*9;
  float bb = b3[c];
  float a0[4] = {bb,bb,bb,bb};
  float a1[4] = {bb,bb,bb,bb};
  #pragma unroll
  for (int q = 0; q < 4; ++q){
    const float* p = &S[(r0+q)*36 + c0];
    float4 t0 = *(const float4*)p;
    float4 t1 = *(const float4*)(p+4);
    float v[6] = {t0.x,t0.y,t0.z,t0.w,t1.x,t1.y};
    if (q < 3){                    // out row r0: dy = q
      #pragma unroll
      for (int dx = 0; dx < 3; ++dx){
        float w = wp[q*3+dx];
        #pragma unroll
        for (int j = 0; j < 4; ++j) a0[j] += w * v[j+dx];
      }
    }
    if (q >= 1){                   // out row r0+1: dy = q-1
      #pragma unroll
      for (int dx = 0; dx < 3; ++dx){
        float w = wp[(q-1)*3+dx];
        #pragma unroll
        for (int j = 0; j < 4; ++j) a1[j] += w * v[j+dx];
      }
    }
  }
  float* cb = comb + (size_t)c*HWX;
  float4* cp0 = (float4*)&cb[(size_t)(y0+r0  )*WWI + x0 + c0];
  float4* cp1 = (float4*)&cb[(size_t)(y0+r0+1)*WWI + x0 + c0];
  float4 o0 = make_float4(a0[0],a0[1],a0[2],a0[3]);
  float4 o1 = make_float4(a1[0],a1[1],a1[2],a1[3]);
  if (!first){
    float4 p0 = *cp0, p1 = *cp1;
    o0.x += p0.x; o0.y += p0.y; o0.z += p0.z; o0.w += p0.w;
    o1.x += p1.x; o1.y += p1.y; o1.z += p1.z; o1.w += p1.w;
  }
  *cp0 = o0;
  *cp1 = o1;
}

// ======== Conv3d #1: 4 d-planes per block, 6 staged planes, row x 4col ====
// Staging: chunk-outer / plane-inner (R10 proven form).
__global__ __launch_bounds__(256) void conv3d1(const float* __restrict__ comb,
    const float* __restrict__ wt, const float* __restrict__ bt,
    bf16* __restrict__ T, float* __restrict__ s1, float* __restrict__ s2){
  __shared__ __align__(16) float S[6][34*36];
  __shared__ float red[4][6];
  const int d0 = blockIdx.z * 4;
  const int x0 = blockIdx.x*32, y0 = blockIdx.y*32;
  const int tid = threadIdx.x;
  #pragma unroll
  for (int k = 0; k < 5; ++k){
    const int i = tid + k*256;
    const bool act = (k < 4) || (tid < 1156 - 1024);
    const int rr = i / 34, cc = i - rr*34;
    const int gy = y0 - 1 + rr, gx = x0 - 1 + cc;
    const bool okxy = act && ((unsigned)gy < HH) && ((unsigned)gx < WWI);
    const int ad = min(max(gy,0),HH-1)*WWI + min(max(gx,0),WWI-1);
    float v[6];
    #pragma unroll
    for (int j = 0; j < 6; ++j){
      const int dz = d0 - 1 + j;
      const float* ip = comb + (size_t)min(max(dz,0),CC-1) * HWX;
      v[j] = act ? ip[ad] : 0.f;
    }
    #pragma unroll
    for (int j = 0; j < 6; ++j){
      const bool ok = okxy && ((unsigned)(d0-1+j) < CC);
      if (act) S[j][rr*36+cc] = ok ? v[j] : 0.f;
    }
  }
  __syncthreads();
  const int cg = tid & 7, row = tid >> 3;
  const int c0 = 4*cg;
  const int lane = tid & 63, wid = tid >> 6;
  for (int dl = 0; dl < 4; ++dl){
    const int d = d0 + dl;
    float acc[3][4];
    #pragma unroll
    for (int oc = 0; oc < 3; ++oc){
      float b = bt[oc];
      #pragma unroll
      for (int j = 0; j < 4; ++j) acc[oc][j] = b;
    }
    #pragma unroll
    for (int dd = 0; dd < 3; ++dd){
      const float* sp = S[dl+dd];
      #pragma unroll
      for (int dy = 0; dy < 3; ++dy){
        const float* p = &sp[(row+dy)*36 + c0];
        float4 t0 = *(const float4*)p;
        float4 t1 = *(const float4*)(p+4);
        float v[6] = {t0.x,t0.y,t0.z,t0.w,t1.x,t1.y};
        #pragma unroll
        for (int dx = 0; dx < 3; ++dx){
          #pragma unroll
          for (int oc = 0; oc < 3; ++oc){
            float w = wt[oc*27 + dd*9 + dy*3 + dx];
            #pragma unroll
            for (int j = 0; j < 4; ++j) acc[oc][j] += w * v[j+dx];
          }
        }
      }
    }
    float vals[6] = {0,0,0,0,0,0};
    #pragma unroll
    for (int oc = 0; oc < 3; ++oc){
      bf16* tp = T + (size_t)(oc*CC + d)*HWX;
      union { ushort4 u; bf16 h[4]; } pk;
      #pragma unroll
      for (int j = 0; j < 4; ++j){
        pk.h[j] = f2b(acc[oc][j]);
        float av = b2f(pk.h[j]);          // stats match stored bf16
        vals[2*oc]   += av;
        vals[2*oc+1] += av*av;
      }
      *(ushort4*)&tp[(size_t)(y0+row)*WWI + x0 + c0] = pk.u;
    }
    #pragma unroll
    for (int o = 32; o > 0; o >>= 1)
      #pragma unroll
      for (int k = 0; k < 6; ++k) vals[k] += __shfl_down(vals[k], o);
    __syncthreads();                      // protect red[] from prev iter
    if (lane == 0)
      #pragma unroll
      for (int k = 0; k < 6; ++k) red[wid][k] = vals[k];
    __syncthreads();
    if (tid == 0){
      #pragma unroll
      for (int oc = 0; oc < 3; ++oc){
        atomicAdd(s1 + oc*CC + d, red[0][2*oc]  +red[1][2*oc]  +red[2][2*oc]  +red[3][2*oc]);
        atomicAdd(s2 + oc*CC + d, red[0][2*oc+1]+red[1][2*oc+1]+red[2][2*oc+1]+red[3][2*oc+1]);
      }
    }
  }
}

// ======== Conv3d #2: DPB=2, 12 relu-norm bf16 planes, pitch 36 ==========
// R10 PROVEN FORM (217 us, VGPR 44, occ 53%). Four restructure attempts
// (dual-acc x2, dl-split, DPB=4) all regressed on VGPR/occupancy/L2
// cliffs — this configuration is the measured optimum for this kernel.
__global__ __launch_bounds__(256) void conv3d2_final(const bf16* __restrict__ T,
    const float* __restrict__ s1i, const float* __restrict__ s2i, float invN,
    const float* __restrict__ wt2, const float* __restrict__ bt2,
    const float* __restrict__ x, float* __restrict__ out){
  __shared__ __align__(16) bf16 S16[12][34*36];   // 29376 B
  const int d0 = blockIdx.z * 2;
  const int x0 = blockIdx.x*32, y0 = blockIdx.y*32;
  const int tid = threadIdx.x;

  // uniform per-plane params (SGPR-pinned)
  float ms[12], rs[12];
  #pragma unroll
  for (int p = 0; p < 12; ++p){
    const int i3 = p >> 2, j = p & 3;
    const int dz = d0 - 1 + j;
    const int ch = i3*CC + min(max(dz,0),CC-1);
    float m, r; mk_norm(s1i, s2i, ch, invN, m, r);
    ms[p] = rfl(m); rs[p] = rfl(r);
  }

  // stage 12 planes in 3 chunks of 12 independent loads (34 x 18 pairs)
  #pragma unroll
  for (int k = 0; k < 3; ++k){
    const int i = tid + k*256;              // index in 34x18 element grid
    const bool act = (k < 2) || (tid < 612 - 512);
    const int rr = i / 18, s = i - rr*18;
    const int gy = y0 - 1 + rr;
    const int gx = x0 - 2 + 2*s;            // even, cols 0..35
    const int ay = min(max(gy,0),HH-1);
    const int ax = min(max(gx,0),WWI-2);    // even, ushort2-safe
    const int aoff = (ay<<9) + ax;
    unsigned int tv[12];
    #pragma unroll
    for (int p = 0; p < 12; ++p){
      const int i3 = p >> 2, j = p & 3;
      const int ch = i3*CC + min(max(d0-1+j,0),CC-1);
      const bf16* tp = T + (size_t)ch*HWX;
      ushort2 t = act ? *(const ushort2*)(tp + aoff) : make_ushort2(0,0);
      tv[p] = (((unsigned)t.y) << 16) | (unsigned)t.x;
    }
    const bool oky  = act && ((unsigned)gy < HH);
    const bool okx0 = (unsigned)gx     < WWI;
    const bool okx1 = (unsigned)(gx+1) < WWI;
    #pragma unroll
    for (int p = 0; p < 12; ++p){
      const int j = p & 3;
      const bool zok = (unsigned)(d0-1+j) < CC;
      const bool bok = oky && zok;
      unsigned lo = tv[p] << 16, hi = tv[p] & 0xffff0000u;
      float f0, f1;
      __builtin_memcpy(&f0, &lo, 4); __builtin_memcpy(&f1, &hi, 4);
      float u0 = (bok && okx0) ? fmaxf((f0 - ms[p]) * rs[p], 0.f) : 0.f;
      float u1 = (bok && okx1) ? fmaxf((f1 - ms[p]) * rs[p], 0.f) : 0.f;
      union { ushort2 u; bf16 h[2]; } pk;
      pk.h[0] = f2b(u0); pk.h[1] = f2b(u1);
      if (act) *(ushort2*)(S16[p] + rr*36 + 2*s) = pk.u;
    }
  }
  __syncthreads();

  const int cg = tid & 7, row = tid >> 3;
  const int c0 = 4*cg;
  for (int dl = 0; dl < 2; ++dl){
    const int d = d0 + dl;
    const float bb = bt2[0];
    float acc[4] = {bb,bb,bb,bb};
    #pragma unroll
    for (int i3 = 0; i3 < 3; ++i3){
      #pragma unroll
      for (int dd = 0; dd < 3; ++dd){
        const bf16* sp = S16[i3*4 + dl + dd];
        #pragma unroll
        for (int dy = 0; dy < 3; ++dy){
          // needed cols (global x0+c0-1 .. x0+c0+4) = LDS cols c0+1 .. c0+6
          const bf16* p = &sp[(row+dy)*36 + c0];
          ushort4 lo = *(const ushort4*)p;
          ushort4 hi = *(const ushort4*)(p+4);
          float v[6] = {u2f(lo.y),u2f(lo.z),u2f(lo.w),
                        u2f(hi.x),u2f(hi.y),u2f(hi.z)};
          #pragma unroll
          for (int dx = 0; dx < 3; ++dx){
            float w = wt2[(i3*3+dd)*9 + dy*3 + dx];
            #pragma unroll
            for (int q = 0; q < 4; ++q) acc[q] += w * v[q+dx];
          }
        }
      }
    }
    size_t gi = (size_t)d*HWX + (size_t)(y0+row)*WWI + x0 + c0;
    float4 xv = *(const float4*)&x[gi];
    float4 o;
    o.x = fmaxf(xv.x / (1.f + __expf(-acc[0])), 0.f);
    o.y = fmaxf(xv.y / (1.f + __expf(-acc[1])), 0.f);
    o.z = fmaxf(xv.z / (1.f + __expf(-acc[2])), 0.f);
    o.w = fmaxf(xv.w / (1.f + __expf(-acc[3])), 0.f);
    *(float4*)&out[gi] = o;
  }
}

extern "C" void kernel_launch(void* const* d_in, const int* in_sizes, int n_in,
                              void* d_out, int out_size, void* d_ws, size_t ws_size,
                              hipStream_t stream){
  const float* x     = (const float*)d_in[0];
  const float* w_wt5 = (const float*)d_in[1];
  const float* b_wt5 = (const float*)d_in[2];
  const float* w_wt9 = (const float*)d_in[3];
  const float* b_wt9 = (const float*)d_in[4];
  const float* w_bt5 = (const float*)d_in[5];
  const float* b_bt5 = (const float*)d_in[6];
  const float* w_bt9 = (const float*)d_in[7];
  const float* b_bt9 = (const float*)d_in[8];
  const float* w_wn  = (const float*)d_in[9];
  const float* b_wn  = (const float*)d_in[10];
  const float* w_t1  = (const float*)d_in[11];
  const float* b_t1  = (const float*)d_in[12];
  const float* w_t2  = (const float*)d_in[13];
  const float* b_t2  = (const float*)d_in[14];
  float* out = (float*)d_out;

  // ---- workspace layout ----
  char* ws = (char*)d_ws;
  float* A    = (float*)ws;                        // branch dwconv out
  float* comb = (float*)(ws + 2*(size_t)CHWX*4);   // accumulator
  bf16*  T    = (bf16*)ws;                         // 3*CHWX bf16 overlay
  float* stats = comb + (size_t)CHWX;
  float* s1 = stats;        // 704
  float* s2 = stats + 704;  // 704

  hipMemsetAsync(s1, 0, 1408 * sizeof(float), stream);

  dim3 blk(256);
  dim3 gridMor(WWI/32, HH/64, CC);          // (16,8,64) morphdw 32x64 tile
  dim3 gridC3(WWI/32, HH/64, CC);           // (16,8,64) conv3_acc 32x64 tile
  dim3 gridM4(WWI/32, HH/32, CC/4);         // (16,16,16)
  dim3 gridT2(WWI/32, HH/32, CC/2);         // (16,16,32) conv3d2 DPB=2
  dim3 gridD(64, 1, CC);                    // diff grid-stride x4
  float invHW = 1.f / (float)HWX;

  int first = 1;
  for (int ki = 0; ki < 2; ++ki){
    for (int br = 0; br < 2; ++br){
      int st = (ki * 2 + br) * 2;
      if (ki == 0){
        if (br == 0) morphdw<2, true ><<<gridMor, blk, 0, stream>>>(x, w_wt5, b_wt5, A, s1+st*64, s2+st*64);
        else         morphdw<2, false><<<gridMor, blk, 0, stream>>>(x, w_bt5, b_bt5, A, s1+st*64, s2+st*64);
      } else {
        if (br == 0) morphdw<4, true ><<<gridMor, blk, 0, stream>>>(x, w_wt9, b_wt9, A, s1+st*64, s2+st*64);
        else         morphdw<4, false><<<gridMor, blk, 0, stream>>>(x, w_bt9, b_bt9, A, s1+st*64, s2+st*64);
      }
      float sgn = (br == 0) ? -1.f : 1.f;   // WTHAM: x - wth ; BTHAM: bth - x
      diff_stats4<<<gridD, blk, 0, stream>>>((const float4*)A, (const float4*)x,
                                             s1 + st*64, s2 + st*64, invHW, sgn,
                                             s1 + (st+1)*64, s2 + (st+1)*64);
      conv3_acc<<<gridC3, blk, 0, stream>>>(A, x, s1 + st*64, s2 + st*64,
                                            s1 + (st+1)*64, s2 + (st+1)*64, invHW,
                                            sgn, w_wn, b_wn, comb, first);
      first = 0;
    }
  }

  // ---- temporal cross ----
  conv3d1<<<gridM4, blk, 0, stream>>>(comb, w_t1, b_t1, T, s1 + 512, s2 + 512);
  conv3d2_final<<<gridT2, blk, 0, stream>>>(T, s1 + 512, s2 + 512, invHW,
                                            w_t2, b_t2, x, out);
}

// Round 14
// 1414.954 us; speedup vs baseline: 1.0486x; 1.0285x over previous
//
#include <hip/hip_runtime.h>
#include <hip/hip_bf16.h>

#define CC 64
#define HH 512
#define WWI 512
#define HWX (HH*WWI)
#define CHWX (CC*HWX)
#define EPSV 1e-5f

using bf16 = __hip_bfloat16;

__device__ __forceinline__ float b2f(bf16 v){ return __bfloat162float(v); }
__device__ __forceinline__ bf16 f2b(float v){ return __float2bfloat16(v); }
__device__ __forceinline__ float u2f(unsigned short u){
  unsigned int x = ((unsigned int)u) << 16;
  float f; __builtin_memcpy(&f, &x, 4); return f;
}
// pin a block-uniform float to an SGPR (keeps it out of the VGPR budget)
__device__ __forceinline__ float rfl(float v){
  int i; __builtin_memcpy(&i, &v, 4);
  i = __builtin_amdgcn_readfirstlane(i);
  float f; __builtin_memcpy(&f, &i, 4); return f;
}

template<bool MX>
__device__ __forceinline__ float opf(float a, float b){
  return MX ? fmaxf(a,b) : fminf(a,b);
}
template<bool MX>
__device__ __forceinline__ float4 opf4(float4 a, float4 b){
  return make_float4(opf<MX>(a.x,b.x), opf<MX>(a.y,b.y),
                     opf<MX>(a.z,b.z), opf<MX>(a.w,b.w));
}

// norm params from raw sums (block-uniform scalar math)
__device__ __forceinline__ void mk_norm(const float* s1, const float* s2, int c,
                                        float invN, float& m, float& r){
  m = s1[c] * invN;
  float v = fmaxf(s2[c] * invN - m * m, 0.f);
  r = rsqrtf(v + EPSV);
}

// 256-thread block. Reduce (v1,v2) across block, atomicAdd into s1,s2.
__device__ __forceinline__ void block_reduce_atomic(float v1, float v2,
                                                    float* s1, float* s2){
  #pragma unroll
  for (int o = 32; o > 0; o >>= 1){
    v1 += __shfl_down(v1, o);
    v2 += __shfl_down(v2, o);
  }
  __shared__ float a1[4], a2[4];
  int lane = threadIdx.x & 63, wid = threadIdx.x >> 6;
  if (lane == 0){ a1[wid] = v1; a2[wid] = v2; }
  __syncthreads();
  if (threadIdx.x == 0){
    atomicAdd(s1, a1[0]+a1[1]+a1[2]+a1[3]);
    atomicAdd(s2, a2[0]+a2[1]+a2[2]+a2[3]);
  }
}

// ======== fused morphology + depthwise conv + stats, float4 LDS passes ====
// CLOSING: maxpool2d then minpool2d (CLOS=true). OPENING: min then max.
// 32x64 tile (TH=64); streamed vertical passes; pass5 = 2 rows/thread.
// (R8 proven form.)
template<int P, bool CLOS>
__global__ __launch_bounds__(256) void morphdw(const float* __restrict__ in,
    const float* __restrict__ wgt, const float* __restrict__ bias,
    float* __restrict__ outF, float* __restrict__ s1, float* __restrict__ s2){
  constexpr int K   = 2*P+1;
  constexpr int TH  = 64;          // tile height
  constexpr int NIx = 32+6*P, NIy = TH+6*P;   // staged input
  constexpr int N1x = 32+4*P, N1y = TH+4*P;   // pool-1 region
  constexpr int N2x = 32+2*P, N2y = TH+2*P;   // morph region (dwconv input)
  constexpr int C1 = N1x/4, C2 = N2x/4;
  constexpr int G1y = N1y/4, G2y = N2y/4;     // streamed 4-row groups
  __shared__ __align__(16) float b0[NIy*NIx];
  __shared__ __align__(16) float b1[NIy*N1x];
  const int c = blockIdx.z;
  const int x0 = blockIdx.x*32, y0 = blockIdx.y*TH;
  const float* ip = in + (size_t)c*HWX;
  const int tid = threadIdx.x;
  // stage input, clamp-to-edge (exact for the first pool)
  for (int i = tid; i < NIy*NIx; i += 256){
    int r = i / NIx, cc = i - r*NIx;
    int gy = min(max(y0 - 3*P + r, 0), HH-1);
    int gx = min(max(x0 - 3*P + cc, 0), WWI-1);
    b0[i] = ip[gy*WWI+gx];
  }
  __syncthreads();
  // pass1: op1 horizontal, b0(NIy x NIx) -> b1(NIy x N1x)
  for (int i = tid; i < NIy*C1; i += 256){
    int r = i / C1, cg = i - r*C1;
    const float* p = &b0[r*NIx + 4*cg];
    float v[4+2*P];
    #pragma unroll
    for (int q = 0; q < (4+2*P)/4; ++q){
      float4 t = *(const float4*)(p + 4*q);
      v[4*q]=t.x; v[4*q+1]=t.y; v[4*q+2]=t.z; v[4*q+3]=t.w;
    }
    float cm = v[3];
    #pragma unroll
    for (int q = 4; q <= 2*P; ++q) cm = opf<CLOS>(cm, v[q]);
    float4 o;
    o.x = opf<CLOS>(opf<CLOS>(opf<CLOS>(cm, v[0]), v[1]), v[2]);
    o.y = opf<CLOS>(opf<CLOS>(opf<CLOS>(cm, v[1]), v[2]), v[2*P+1]);
    o.z = opf<CLOS>(opf<CLOS>(opf<CLOS>(cm, v[2]), v[2*P+1]), v[2*P+2]);
    o.w = opf<CLOS>(opf<CLOS>(opf<CLOS>(cm, v[2*P+1]), v[2*P+2]), v[2*P+3]);
    *(float4*)&b1[r*N1x + 4*cg] = o;
  }
  __syncthreads();
  // pass2: op1 vertical STREAMED (4 out rows/thread) + OOB -> op2-neutral
  for (int i = tid; i < G1y*C1; i += 256){
    int rg = i / C1, cg = i - rg*C1;
    const int R = 4*rg;
    float4 a0, a1, a2, a3;
    #pragma unroll
    for (int q = 0; q < 4+2*P; ++q){
      float4 v = *(const float4*)&b1[(R+q)*N1x + 4*cg];
      if (q == 0) a0 = v; else if (q <= 2*P)            a0 = opf4<CLOS>(a0, v);
      if (q == 1) a1 = v; else if (q > 1 && q <= 2*P+1) a1 = opf4<CLOS>(a1, v);
      if (q == 2) a2 = v; else if (q > 2 && q <= 2*P+2) a2 = opf4<CLOS>(a2, v);
      if (q == 3) a3 = v; else if (q > 3)               a3 = opf4<CLOS>(a3, v);
    }
    const float neut = CLOS ? 3.4e38f : -3.4e38f;
    int gx = x0 - 2*P + 4*cg;
    bool okx0 = (unsigned)(gx  ) < WWI, okx1 = (unsigned)(gx+1) < WWI;
    bool okx2 = (unsigned)(gx+2) < WWI, okx3 = (unsigned)(gx+3) < WWI;
    #pragma unroll
    for (int j = 0; j < 4; ++j){
      float4 m = (j==0)?a0:(j==1)?a1:(j==2)?a2:a3;
      int r = R + j;
      bool oky = (unsigned)(y0 - 2*P + r) < HH;
      m.x = (oky && okx0) ? m.x : neut;
      m.y = (oky && okx1) ? m.y : neut;
      m.z = (oky && okx2) ? m.z : neut;
      m.w = (oky && okx3) ? m.w : neut;
      *(float4*)&b0[r*N1x + 4*cg] = m;
    }
  }
  __syncthreads();
  // pass3: op2 horizontal, b0(N1y x N1x) -> b1(N1y x N2x)
  for (int i = tid; i < N1y*C2; i += 256){
    int r = i / C2, cg = i - r*C2;
    const float* p = &b0[r*N1x + 4*cg];
    float v[4+2*P];
    #pragma unroll
    for (int q = 0; q < (4+2*P)/4; ++q){
      float4 t = *(const float4*)(p + 4*q);
      v[4*q]=t.x; v[4*q+1]=t.y; v[4*q+2]=t.z; v[4*q+3]=t.w;
    }
    float cm = v[3];
    #pragma unroll
    for (int q = 4; q <= 2*P; ++q) cm = opf<!CLOS>(cm, v[q]);
    float4 o;
    o.x = opf<!CLOS>(opf<!CLOS>(opf<!CLOS>(cm, v[0]), v[1]), v[2]);
    o.y = opf<!CLOS>(opf<!CLOS>(opf<!CLOS>(cm, v[1]), v[2]), v[2*P+1]);
    o.z = opf<!CLOS>(opf<!CLOS>(opf<!CLOS>(cm, v[2]), v[2*P+1]), v[2*P+2]);
    o.w = opf<!CLOS>(opf<!CLOS>(opf<!CLOS>(cm, v[2*P+1]), v[2*P+2]), v[2*P+3]);
    *(float4*)&b1[r*N2x + 4*cg] = o;
  }
  __syncthreads();
  // pass4: op2 vertical STREAMED (4 out rows/thread) + OOB -> 0 (conv pad)
  for (int i = tid; i < G2y*C2; i += 256){
    int rg = i / C2, cg = i - rg*C2;
    const int R = 4*rg;
    float4 a0, a1, a2, a3;
    #pragma unroll
    for (int q = 0; q < 4+2*P; ++q){
      float4 v = *(const float4*)&b1[(R+q)*N2x + 4*cg];
      if (q == 0) a0 = v; else if (q <= 2*P)            a0 = opf4<!CLOS>(a0, v);
      if (q == 1) a1 = v; else if (q > 1 && q <= 2*P+1) a1 = opf4<!CLOS>(a1, v);
      if (q == 2) a2 = v; else if (q > 2 && q <= 2*P+2) a2 = opf4<!CLOS>(a2, v);
      if (q == 3) a3 = v; else if (q > 3)               a3 = opf4<!CLOS>(a3, v);
    }
    int gx = x0 - P + 4*cg;
    bool okx0 = (unsigned)(gx  ) < WWI, okx1 = (unsigned)(gx+1) < WWI;
    bool okx2 = (unsigned)(gx+2) < WWI, okx3 = (unsigned)(gx+3) < WWI;
    #pragma unroll
    for (int j = 0; j < 4; ++j){
      float4 m = (j==0)?a0:(j==1)?a1:(j==2)?a2:a3;
      int r = R + j;
      bool oky = (unsigned)(y0 - P + r) < HH;
      m.x = (oky && okx0) ? m.x : 0.f;
      m.y = (oky && okx1) ? m.y : 0.f;
      m.z = (oky && okx2) ? m.z : 0.f;
      m.w = (oky && okx3) ? m.w : 0.f;
      *(float4*)&b0[r*N2x + 4*cg] = m;
    }
  }
  __syncthreads();
  // pass5: dwconv KxK, thread = 2 rows x 4 cols, stream K+1 rows once
  const float* wp = wgt + c*K*K;
  const int cg = tid & 7, rg = tid >> 3;     // rg in [0,32)
  const int c0 = 4*cg, r0 = 2*rg;
  float bb = bias[c];
  float a0=bb, a1=bb, a2=bb, a3=bb;          // row r0
  float e0=bb, e1=bb, e2=bb, e3=bb;          // row r0+1
  #pragma unroll
  for (int q = 0; q <= K; ++q){
    float v[4+2*P];
    const float* p = &b0[(r0+q)*N2x + c0];
    #pragma unroll
    for (int t = 0; t < (4+2*P)/4; ++t){
      float4 f = *(const float4*)(p + 4*t);
      v[4*t]=f.x; v[4*t+1]=f.y; v[4*t+2]=f.z; v[4*t+3]=f.w;
    }
    if (q < K){                    // acc row r0: dy = q
      #pragma unroll
      for (int dx = 0; dx < K; ++dx){
        float w = wp[q*K+dx];
        a0 += w*v[dx]; a1 += w*v[dx+1]; a2 += w*v[dx+2]; a3 += w*v[dx+3];
      }
    }
    if (q >= 1){                   // acc row r0+1: dy = q-1
      #pragma unroll
      for (int dx = 0; dx < K; ++dx){
        float w = wp[(q-1)*K+dx];
        e0 += w*v[dx]; e1 += w*v[dx+1]; e2 += w*v[dx+2]; e3 += w*v[dx+3];
      }
    }
  }
  float* op = outF + (size_t)c*HWX;
  *(float4*)&op[(size_t)(y0+r0  )*WWI + x0 + c0] = make_float4(a0,a1,a2,a3);
  *(float4*)&op[(size_t)(y0+r0+1)*WWI + x0 + c0] = make_float4(e0,e1,e2,e3);
  block_reduce_atomic((a0+a1+a2+a3) + (e0+e1+e2+e3),
                      (a0*a0+a1*a1+a2*a2+a3*a3) + (e0*e0+e1*e1+e2*e2+e3*e3),
                      s1+c, s2+c);
}

// -------- stats of d = sgn*(relu(norm(A)) - x); grid-stride x4 ----------
__global__ __launch_bounds__(256) void diff_stats4(const float4* __restrict__ A,
    const float4* __restrict__ x,
    const float* __restrict__ s1i, const float* __restrict__ s2i, float invN,
    float sgn, float* __restrict__ s1, float* __restrict__ s2){
  int c = blockIdx.z;
  float m, r;
  mk_norm(s1i, s2i, c, invN, m, r);
  size_t base = (size_t)c * (HWX/4) + blockIdx.x * 1024 + threadIdx.x;
  float sv = 0.f, sq = 0.f;
  #pragma unroll
  for (int k = 0; k < 4; ++k){
    size_t i = base + k*256;
    float4 f = A[i], xv = x[i];
    float d0 = sgn * (fmaxf((f.x - m) * r, 0.f) - xv.x);
    float d1 = sgn * (fmaxf((f.y - m) * r, 0.f) - xv.y);
    float d2 = sgn * (fmaxf((f.z - m) * r, 0.f) - xv.z);
    float d3 = sgn * (fmaxf((f.w - m) * r, 0.f) - xv.w);
    sv += d0+d1+d2+d3;
    sq += d0*d0+d1*d1+d2*d2+d3*d3;
  }
  block_reduce_atomic(sv, sq, s1 + c, s2 + c);
}

// ======== 3x3 dwconv of norm(d); d recomputed from A,x; row x 4col =======
// R10 EXACT FORM (chunked fully-unrolled staging, TH=32). R13's TH=64
// variant is the only diff vs the 1416us R10 measurement — this round
// discriminates "TH=64 costs ~40us" from "totals are +-40us noisy".
__global__ __launch_bounds__(256) void conv3_acc(const float* __restrict__ A,
    const float* __restrict__ x,
    const float* __restrict__ s1A, const float* __restrict__ s2A,
    const float* __restrict__ s1D, const float* __restrict__ s2D, float invN,
    float sgn, const float* __restrict__ w3, const float* __restrict__ b3,
    float* __restrict__ comb, int first){
  __shared__ __align__(16) float S[34*36];
  const int c = blockIdx.z;
  const int x0 = blockIdx.x*32, y0 = blockIdx.y*32;
  float mA_, rA_, mD_, rD_;
  mk_norm(s1A, s2A, c, invN, mA_, rA_);
  mk_norm(s1D, s2D, c, invN, mD_, rD_);
  const float mA = rfl(mA_), rA = rfl(rA_), mD = rfl(mD_), rD = rfl(rD_);
  const float* ap = A + (size_t)c*HWX;
  const float* xp = x + (size_t)c*HWX;
  const int tid = threadIdx.x;
  // 34*34 = 1156 = 4*256 + 132 -> 5 chunks, unrolled for load overlap
  #pragma unroll
  for (int k = 0; k < 5; ++k){
    const int i = tid + k*256;
    const bool act = (k < 4) || (tid < 1156 - 1024);
    const int rr = i / 34, cc = i - rr*34;
    const int gy = y0 - 1 + rr, gx = x0 - 1 + cc;
    const bool ok = act && ((unsigned)gy < HH) && ((unsigned)gx < WWI);
    const int ad = min(max(gy,0),HH-1)*WWI + min(max(gx,0),WWI-1);
    float av = act ? ap[ad] : 0.f;
    float xv = act ? xp[ad] : 0.f;
    float dval = sgn * (fmaxf((av - mA) * rA, 0.f) - xv);
    if (act) S[rr*36+cc] = ok ? (dval - mD) * rD : 0.f;
  }
  __syncthreads();
  const int cg = tid & 7, row = tid >> 3;
  const int c0 = 4*cg;
  const float* wp = w3 + c*9;
  float bb = b3[c];
  float acc[4] = {bb,bb,bb,bb};
  #pragma unroll
  for (int dy = 0; dy < 3; ++dy){
    const float* p = &S[(row+dy)*36 + c0];
    float4 t0 = *(const float4*)p;
    float4 t1 = *(const float4*)(p+4);
    float v[6] = {t0.x,t0.y,t0.z,t0.w,t1.x,t1.y};
    #pragma unroll
    for (int dx = 0; dx < 3; ++dx){
      float w = wp[dy*3+dx];
      #pragma unroll
      for (int j = 0; j < 4; ++j) acc[j] += w * v[j+dx];
    }
  }
  float4* cp = (float4*)&comb[(size_t)c*HWX + (y0+row)*WWI + x0 + c0];
  float4 o = make_float4(acc[0],acc[1],acc[2],acc[3]);
  if (!first){
    float4 prev = *cp;
    o.x += prev.x; o.y += prev.y; o.z += prev.z; o.w += prev.w;
  }
  *cp = o;
}

// ======== Conv3d #1: 4 d-planes per block, 6 staged planes, row x 4col ====
// Staging: chunk-outer / plane-inner (R10 proven form).
__global__ __launch_bounds__(256) void conv3d1(const float* __restrict__ comb,
    const float* __restrict__ wt, const float* __restrict__ bt,
    bf16* __restrict__ T, float* __restrict__ s1, float* __restrict__ s2){
  __shared__ __align__(16) float S[6][34*36];
  __shared__ float red[4][6];
  const int d0 = blockIdx.z * 4;
  const int x0 = blockIdx.x*32, y0 = blockIdx.y*32;
  const int tid = threadIdx.x;
  #pragma unroll
  for (int k = 0; k < 5; ++k){
    const int i = tid + k*256;
    const bool act = (k < 4) || (tid < 1156 - 1024);
    const int rr = i / 34, cc = i - rr*34;
    const int gy = y0 - 1 + rr, gx = x0 - 1 + cc;
    const bool okxy = act && ((unsigned)gy < HH) && ((unsigned)gx < WWI);
    const int ad = min(max(gy,0),HH-1)*WWI + min(max(gx,0),WWI-1);
    float v[6];
    #pragma unroll
    for (int j = 0; j < 6; ++j){
      const int dz = d0 - 1 + j;
      const float* ip = comb + (size_t)min(max(dz,0),CC-1) * HWX;
      v[j] = act ? ip[ad] : 0.f;
    }
    #pragma unroll
    for (int j = 0; j < 6; ++j){
      const bool ok = okxy && ((unsigned)(d0-1+j) < CC);
      if (act) S[j][rr*36+cc] = ok ? v[j] : 0.f;
    }
  }
  __syncthreads();
  const int cg = tid & 7, row = tid >> 3;
  const int c0 = 4*cg;
  const int lane = tid & 63, wid = tid >> 6;
  for (int dl = 0; dl < 4; ++dl){
    const int d = d0 + dl;
    float acc[3][4];
    #pragma unroll
    for (int oc = 0; oc < 3; ++oc){
      float b = bt[oc];
      #pragma unroll
      for (int j = 0; j < 4; ++j) acc[oc][j] = b;
    }
    #pragma unroll
    for (int dd = 0; dd < 3; ++dd){
      const float* sp = S[dl+dd];
      #pragma unroll
      for (int dy = 0; dy < 3; ++dy){
        const float* p = &sp[(row+dy)*36 + c0];
        float4 t0 = *(const float4*)p;
        float4 t1 = *(const float4*)(p+4);
        float v[6] = {t0.x,t0.y,t0.z,t0.w,t1.x,t1.y};
        #pragma unroll
        for (int dx = 0; dx < 3; ++dx){
          #pragma unroll
          for (int oc = 0; oc < 3; ++oc){
            float w = wt[oc*27 + dd*9 + dy*3 + dx];
            #pragma unroll
            for (int j = 0; j < 4; ++j) acc[oc][j] += w * v[j+dx];
          }
        }
      }
    }
    float vals[6] = {0,0,0,0,0,0};
    #pragma unroll
    for (int oc = 0; oc < 3; ++oc){
      bf16* tp = T + (size_t)(oc*CC + d)*HWX;
      union { ushort4 u; bf16 h[4]; } pk;
      #pragma unroll
      for (int j = 0; j < 4; ++j){
        pk.h[j] = f2b(acc[oc][j]);
        float av = b2f(pk.h[j]);          // stats match stored bf16
        vals[2*oc]   += av;
        vals[2*oc+1] += av*av;
      }
      *(ushort4*)&tp[(size_t)(y0+row)*WWI + x0 + c0] = pk.u;
    }
    #pragma unroll
    for (int o = 32; o > 0; o >>= 1)
      #pragma unroll
      for (int k = 0; k < 6; ++k) vals[k] += __shfl_down(vals[k], o);
    __syncthreads();                      // protect red[] from prev iter
    if (lane == 0)
      #pragma unroll
      for (int k = 0; k < 6; ++k) red[wid][k] = vals[k];
    __syncthreads();
    if (tid == 0){
      #pragma unroll
      for (int oc = 0; oc < 3; ++oc){
        atomicAdd(s1 + oc*CC + d, red[0][2*oc]  +red[1][2*oc]  +red[2][2*oc]  +red[3][2*oc]);
        atomicAdd(s2 + oc*CC + d, red[0][2*oc+1]+red[1][2*oc+1]+red[2][2*oc+1]+red[3][2*oc+1]);
      }
    }
  }
}

// ======== Conv3d #2: DPB=2, 12 relu-norm bf16 planes, pitch 36 ==========
// R10 PROVEN FORM (217 us, VGPR 44, occ 53%). Four restructure attempts
// (dual-acc x2, dl-split, DPB=4) all regressed on VGPR/occupancy/L2
// cliffs — this configuration is the measured optimum for this kernel.
__global__ __launch_bounds__(256) void conv3d2_final(const bf16* __restrict__ T,
    const float* __restrict__ s1i, const float* __restrict__ s2i, float invN,
    const float* __restrict__ wt2, const float* __restrict__ bt2,
    const float* __restrict__ x, float* __restrict__ out){
  __shared__ __align__(16) bf16 S16[12][34*36];   // 29376 B
  const int d0 = blockIdx.z * 2;
  const int x0 = blockIdx.x*32, y0 = blockIdx.y*32;
  const int tid = threadIdx.x;

  // uniform per-plane params (SGPR-pinned)
  float ms[12], rs[12];
  #pragma unroll
  for (int p = 0; p < 12; ++p){
    const int i3 = p >> 2, j = p & 3;
    const int dz = d0 - 1 + j;
    const int ch = i3*CC + min(max(dz,0),CC-1);
    float m, r; mk_norm(s1i, s2i, ch, invN, m, r);
    ms[p] = rfl(m); rs[p] = rfl(r);
  }

  // stage 12 planes in 3 chunks of 12 independent loads (34 x 18 pairs)
  #pragma unroll
  for (int k = 0; k < 3; ++k){
    const int i = tid + k*256;              // index in 34x18 element grid
    const bool act = (k < 2) || (tid < 612 - 512);
    const int rr = i / 18, s = i - rr*18;
    const int gy = y0 - 1 + rr;
    const int gx = x0 - 2 + 2*s;            // even, cols 0..35
    const int ay = min(max(gy,0),HH-1);
    const int ax = min(max(gx,0),WWI-2);    // even, ushort2-safe
    const int aoff = (ay<<9) + ax;
    unsigned int tv[12];
    #pragma unroll
    for (int p = 0; p < 12; ++p){
      const int i3 = p >> 2, j = p & 3;
      const int ch = i3*CC + min(max(d0-1+j,0),CC-1);
      const bf16* tp = T + (size_t)ch*HWX;
      ushort2 t = act ? *(const ushort2*)(tp + aoff) : make_ushort2(0,0);
      tv[p] = (((unsigned)t.y) << 16) | (unsigned)t.x;
    }
    const bool oky  = act && ((unsigned)gy < HH);
    const bool okx0 = (unsigned)gx     < WWI;
    const bool okx1 = (unsigned)(gx+1) < WWI;
    #pragma unroll
    for (int p = 0; p < 12; ++p){
      const int j = p & 3;
      const bool zok = (unsigned)(d0-1+j) < CC;
      const bool bok = oky && zok;
      unsigned lo = tv[p] << 16, hi = tv[p] & 0xffff0000u;
      float f0, f1;
      __builtin_memcpy(&f0, &lo, 4); __builtin_memcpy(&f1, &hi, 4);
      float u0 = (bok && okx0) ? fmaxf((f0 - ms[p]) * rs[p], 0.f) : 0.f;
      float u1 = (bok && okx1) ? fmaxf((f1 - ms[p]) * rs[p], 0.f) : 0.f;
      union { ushort2 u; bf16 h[2]; } pk;
      pk.h[0] = f2b(u0); pk.h[1] = f2b(u1);
      if (act) *(ushort2*)(S16[p] + rr*36 + 2*s) = pk.u;
    }
  }
  __syncthreads();

  const int cg = tid & 7, row = tid >> 3;
  const int c0 = 4*cg;
  for (int dl = 0; dl < 2; ++dl){
    const int d = d0 + dl;
    const float bb = bt2[0];
    float acc[4] = {bb,bb,bb,bb};
    #pragma unroll
    for (int i3 = 0; i3 < 3; ++i3){
      #pragma unroll
      for (int dd = 0; dd < 3; ++dd){
        const bf16* sp = S16[i3*4 + dl + dd];
        #pragma unroll
        for (int dy = 0; dy < 3; ++dy){
          // needed cols (global x0+c0-1 .. x0+c0+4) = LDS cols c0+1 .. c0+6
          const bf16* p = &sp[(row+dy)*36 + c0];
          ushort4 lo = *(const ushort4*)p;
          ushort4 hi = *(const ushort4*)(p+4);
          float v[6] = {u2f(lo.y),u2f(lo.z),u2f(lo.w),
                        u2f(hi.x),u2f(hi.y),u2f(hi.z)};
          #pragma unroll
          for (int dx = 0; dx < 3; ++dx){
            float w = wt2[(i3*3+dd)*9 + dy*3 + dx];
            #pragma unroll
            for (int q = 0; q < 4; ++q) acc[q] += w * v[q+dx];
          }
        }
      }
    }
    size_t gi = (size_t)d*HWX + (size_t)(y0+row)*WWI + x0 + c0;
    float4 xv = *(const float4*)&x[gi];
    float4 o;
    o.x = fmaxf(xv.x / (1.f + __expf(-acc[0])), 0.f);
    o.y = fmaxf(xv.y / (1.f + __expf(-acc[1])), 0.f);
    o.z = fmaxf(xv.z / (1.f + __expf(-acc[2])), 0.f);
    o.w = fmaxf(xv.w / (1.f + __expf(-acc[3])), 0.f);
    *(float4*)&out[gi] = o;
  }
}

extern "C" void kernel_launch(void* const* d_in, const int* in_sizes, int n_in,
                              void* d_out, int out_size, void* d_ws, size_t ws_size,
                              hipStream_t stream){
  const float* x     = (const float*)d_in[0];
  const float* w_wt5 = (const float*)d_in[1];
  const float* b_wt5 = (const float*)d_in[2];
  const float* w_wt9 = (const float*)d_in[3];
  const float* b_wt9 = (const float*)d_in[4];
  const float* w_bt5 = (const float*)d_in[5];
  const float* b_bt5 = (const float*)d_in[6];
  const float* w_bt9 = (const float*)d_in[7];
  const float* b_bt9 = (const float*)d_in[8];
  const float* w_wn  = (const float*)d_in[9];
  const float* b_wn  = (const float*)d_in[10];
  const float* w_t1  = (const float*)d_in[11];
  const float* b_t1  = (const float*)d_in[12];
  const float* w_t2  = (const float*)d_in[13];
  const float* b_t2  = (const float*)d_in[14];
  float* out = (float*)d_out;

  // ---- workspace layout ----
  char* ws = (char*)d_ws;
  float* A    = (float*)ws;                        // branch dwconv out
  float* comb = (float*)(ws + 2*(size_t)CHWX*4);   // accumulator
  bf16*  T    = (bf16*)ws;                         // 3*CHWX bf16 overlay
  float* stats = comb + (size_t)CHWX;
  float* s1 = stats;        // 704
  float* s2 = stats + 704;  // 704

  hipMemsetAsync(s1, 0, 1408 * sizeof(float), stream);

  dim3 blk(256);
  dim3 gridMor(WWI/32, HH/64, CC);          // (16,8,64) morphdw 32x64 tile
  dim3 gridC3(WWI/32, HH/32, CC);           // (16,16,64) conv3_acc 32x32 tile
  dim3 gridM4(WWI/32, HH/32, CC/4);         // (16,16,16)
  dim3 gridT2(WWI/32, HH/32, CC/2);         // (16,16,32) conv3d2 DPB=2
  dim3 gridD(64, 1, CC);                    // diff grid-stride x4
  float invHW = 1.f / (float)HWX;

  int first = 1;
  for (int ki = 0; ki < 2; ++ki){
    for (int br = 0; br < 2; ++br){
      int st = (ki * 2 + br) * 2;
      if (ki == 0){
        if (br == 0) morphdw<2, true ><<<gridMor, blk, 0, stream>>>(x, w_wt5, b_wt5, A, s1+st*64, s2+st*64);
        else         morphdw<2, false><<<gridMor, blk, 0, stream>>>(x, w_bt5, b_bt5, A, s1+st*64, s2+st*64);
      } else {
        if (br == 0) morphdw<4, true ><<<gridMor, blk, 0, stream>>>(x, w_wt9, b_wt9, A, s1+st*64, s2+st*64);
        else         morphdw<4, false><<<gridMor, blk, 0, stream>>>(x, w_bt9, b_bt9, A, s1+st*64, s2+st*64);
      }
      float sgn = (br == 0) ? -1.f : 1.f;   // WTHAM: x - wth ; BTHAM: bth - x
      diff_stats4<<<gridD, blk, 0, stream>>>((const float4*)A, (const float4*)x,
                                             s1 + st*64, s2 + st*64, invHW, sgn,
                                             s1 + (st+1)*64, s2 + (st+1)*64);
      conv3_acc<<<gridC3, blk, 0, stream>>>(A, x, s1 + st*64, s2 + st*64,
                                            s1 + (st+1)*64, s2 + (st+1)*64, invHW,
                                            sgn, w_wn, b_wn, comb, first);
      first = 0;
    }
  }

  // ---- temporal cross ----
  conv3d1<<<gridM4, blk, 0, stream>>>(comb, w_t1, b_t1, T, s1 + 512, s2 + 512);
  conv3d2_final<<<gridT2, blk, 0, stream>>>(T, s1 + 512, s2 + 512, invHW,
                                            w_t2, b_t2, x, out);
}

// Round 15
// 1337.161 us; speedup vs baseline: 1.1096x; 1.0582x over previous
//
#include <hip/hip_runtime.h>
#include <hip/hip_bf16.h>

#define CC 64
#define HH 512
#define WWI 512
#define HWX (HH*WWI)
#define CHWX (CC*HWX)
#define EPSV 1e-5f

using bf16 = __hip_bfloat16;

__device__ __forceinline__ float b2f(bf16 v){ return __bfloat162float(v); }
__device__ __forceinline__ bf16 f2b(float v){ return __float2bfloat16(v); }
__device__ __forceinline__ float u2f(unsigned short u){
  unsigned int x = ((unsigned int)u) << 16;
  float f; __builtin_memcpy(&f, &x, 4); return f;
}
// pin a block-uniform float to an SGPR (keeps it out of the VGPR budget)
__device__ __forceinline__ float rfl(float v){
  int i; __builtin_memcpy(&i, &v, 4);
  i = __builtin_amdgcn_readfirstlane(i);
  float f; __builtin_memcpy(&f, &i, 4); return f;
}

template<bool MX>
__device__ __forceinline__ float opf(float a, float b){
  return MX ? fmaxf(a,b) : fminf(a,b);
}
template<bool MX>
__device__ __forceinline__ float4 opf4(float4 a, float4 b){
  return make_float4(opf<MX>(a.x,b.x), opf<MX>(a.y,b.y),
                     opf<MX>(a.z,b.z), opf<MX>(a.w,b.w));
}

// norm params from raw sums (block-uniform scalar math)
__device__ __forceinline__ void mk_norm(const float* s1, const float* s2, int c,
                                        float invN, float& m, float& r){
  m = s1[c] * invN;
  float v = fmaxf(s2[c] * invN - m * m, 0.f);
  r = rsqrtf(v + EPSV);
}

// 256-thread block. Reduce (v1,v2) across block, atomicAdd into s1,s2.
__device__ __forceinline__ void block_reduce_atomic(float v1, float v2,
                                                    float* s1, float* s2){
  #pragma unroll
  for (int o = 32; o > 0; o >>= 1){
    v1 += __shfl_down(v1, o);
    v2 += __shfl_down(v2, o);
  }
  __shared__ float a1[4], a2[4];
  int lane = threadIdx.x & 63, wid = threadIdx.x >> 6;
  if (lane == 0){ a1[wid] = v1; a2[wid] = v2; }
  __syncthreads();
  if (threadIdx.x == 0){
    atomicAdd(s1, a1[0]+a1[1]+a1[2]+a1[3]);
    atomicAdd(s2, a2[0]+a2[1]+a2[2]+a2[3]);
  }
}

// ======== fused morphology + depthwise conv + stats, float4 LDS passes ====
// CLOSING: maxpool2d then minpool2d (CLOS=true). OPENING: min then max.
// 32x64 tile (TH=64); streamed vertical passes; pass5 = 2 rows/thread.
// R15: input staging CHUNK-UNROLLED (R5 lever) — was a runtime grid-stride
// loop = ~20 serialized load->ds_write round-trips/thread; unrolled chunks
// let the independent global loads batch. Values identical -> bit-exact.
template<int P, bool CLOS>
__global__ __launch_bounds__(256) void morphdw(const float* __restrict__ in,
    const float* __restrict__ wgt, const float* __restrict__ bias,
    float* __restrict__ outF, float* __restrict__ s1, float* __restrict__ s2){
  constexpr int K   = 2*P+1;
  constexpr int TH  = 64;          // tile height
  constexpr int NIx = 32+6*P, NIy = TH+6*P;   // staged input
  constexpr int N1x = 32+4*P, N1y = TH+4*P;   // pool-1 region
  constexpr int N2x = 32+2*P, N2y = TH+2*P;   // morph region (dwconv input)
  constexpr int C1 = N1x/4, C2 = N2x/4;
  constexpr int G1y = N1y/4, G2y = N2y/4;     // streamed 4-row groups
  constexpr int TOT = NIy*NIx;
  constexpr int NCH = (TOT + 255)/256;        // staging chunks
  __shared__ __align__(16) float b0[NIy*NIx];
  __shared__ __align__(16) float b1[NIy*N1x];
  const int c = blockIdx.z;
  const int x0 = blockIdx.x*32, y0 = blockIdx.y*TH;
  const float* ip = in + (size_t)c*HWX;
  const int tid = threadIdx.x;
  // stage input, clamp-to-edge (exact for the first pool), chunk-unrolled
  #pragma unroll
  for (int k = 0; k < NCH; ++k){
    const int i = tid + k*256;
    const bool act = (k < NCH-1) || (tid < TOT - (NCH-1)*256);
    const int r = i / NIx, cc = i - r*NIx;
    const int gy = min(max(y0 - 3*P + r, 0), HH-1);
    const int gx = min(max(x0 - 3*P + cc, 0), WWI-1);
    float v = act ? ip[gy*WWI+gx] : 0.f;
    if (act) b0[i] = v;
  }
  __syncthreads();
  // pass1: op1 horizontal, b0(NIy x NIx) -> b1(NIy x N1x)
  for (int i = tid; i < NIy*C1; i += 256){
    int r = i / C1, cg = i - r*C1;
    const float* p = &b0[r*NIx + 4*cg];
    float v[4+2*P];
    #pragma unroll
    for (int q = 0; q < (4+2*P)/4; ++q){
      float4 t = *(const float4*)(p + 4*q);
      v[4*q]=t.x; v[4*q+1]=t.y; v[4*q+2]=t.z; v[4*q+3]=t.w;
    }
    float cm = v[3];
    #pragma unroll
    for (int q = 4; q <= 2*P; ++q) cm = opf<CLOS>(cm, v[q]);
    float4 o;
    o.x = opf<CLOS>(opf<CLOS>(opf<CLOS>(cm, v[0]), v[1]), v[2]);
    o.y = opf<CLOS>(opf<CLOS>(opf<CLOS>(cm, v[1]), v[2]), v[2*P+1]);
    o.z = opf<CLOS>(opf<CLOS>(opf<CLOS>(cm, v[2]), v[2*P+1]), v[2*P+2]);
    o.w = opf<CLOS>(opf<CLOS>(opf<CLOS>(cm, v[2*P+1]), v[2*P+2]), v[2*P+3]);
    *(float4*)&b1[r*N1x + 4*cg] = o;
  }
  __syncthreads();
  // pass2: op1 vertical STREAMED (4 out rows/thread) + OOB -> op2-neutral
  for (int i = tid; i < G1y*C1; i += 256){
    int rg = i / C1, cg = i - rg*C1;
    const int R = 4*rg;
    float4 a0, a1, a2, a3;
    #pragma unroll
    for (int q = 0; q < 4+2*P; ++q){
      float4 v = *(const float4*)&b1[(R+q)*N1x + 4*cg];
      if (q == 0) a0 = v; else if (q <= 2*P)            a0 = opf4<CLOS>(a0, v);
      if (q == 1) a1 = v; else if (q > 1 && q <= 2*P+1) a1 = opf4<CLOS>(a1, v);
      if (q == 2) a2 = v; else if (q > 2 && q <= 2*P+2) a2 = opf4<CLOS>(a2, v);
      if (q == 3) a3 = v; else if (q > 3)               a3 = opf4<CLOS>(a3, v);
    }
    const float neut = CLOS ? 3.4e38f : -3.4e38f;
    int gx = x0 - 2*P + 4*cg;
    bool okx0 = (unsigned)(gx  ) < WWI, okx1 = (unsigned)(gx+1) < WWI;
    bool okx2 = (unsigned)(gx+2) < WWI, okx3 = (unsigned)(gx+3) < WWI;
    #pragma unroll
    for (int j = 0; j < 4; ++j){
      float4 m = (j==0)?a0:(j==1)?a1:(j==2)?a2:a3;
      int r = R + j;
      bool oky = (unsigned)(y0 - 2*P + r) < HH;
      m.x = (oky && okx0) ? m.x : neut;
      m.y = (oky && okx1) ? m.y : neut;
      m.z = (oky && okx2) ? m.z : neut;
      m.w = (oky && okx3) ? m.w : neut;
      *(float4*)&b0[r*N1x + 4*cg] = m;
    }
  }
  __syncthreads();
  // pass3: op2 horizontal, b0(N1y x N1x) -> b1(N1y x N2x)
  for (int i = tid; i < N1y*C2; i += 256){
    int r = i / C2, cg = i - r*C2;
    const float* p = &b0[r*N1x + 4*cg];
    float v[4+2*P];
    #pragma unroll
    for (int q = 0; q < (4+2*P)/4; ++q){
      float4 t = *(const float4*)(p + 4*q);
      v[4*q]=t.x; v[4*q+1]=t.y; v[4*q+2]=t.z; v[4*q+3]=t.w;
    }
    float cm = v[3];
    #pragma unroll
    for (int q = 4; q <= 2*P; ++q) cm = opf<!CLOS>(cm, v[q]);
    float4 o;
    o.x = opf<!CLOS>(opf<!CLOS>(opf<!CLOS>(cm, v[0]), v[1]), v[2]);
    o.y = opf<!CLOS>(opf<!CLOS>(opf<!CLOS>(cm, v[1]), v[2]), v[2*P+1]);
    o.z = opf<!CLOS>(opf<!CLOS>(opf<!CLOS>(cm, v[2]), v[2*P+1]), v[2*P+2]);
    o.w = opf<!CLOS>(opf<!CLOS>(opf<!CLOS>(cm, v[2*P+1]), v[2*P+2]), v[2*P+3]);
    *(float4*)&b1[r*N2x + 4*cg] = o;
  }
  __syncthreads();
  // pass4: op2 vertical STREAMED (4 out rows/thread) + OOB -> 0 (conv pad)
  for (int i = tid; i < G2y*C2; i += 256){
    int rg = i / C2, cg = i - rg*C2;
    const int R = 4*rg;
    float4 a0, a1, a2, a3;
    #pragma unroll
    for (int q = 0; q < 4+2*P; ++q){
      float4 v = *(const float4*)&b1[(R+q)*N2x + 4*cg];
      if (q == 0) a0 = v; else if (q <= 2*P)            a0 = opf4<!CLOS>(a0, v);
      if (q == 1) a1 = v; else if (q > 1 && q <= 2*P+1) a1 = opf4<!CLOS>(a1, v);
      if (q == 2) a2 = v; else if (q > 2 && q <= 2*P+2) a2 = opf4<!CLOS>(a2, v);
      if (q == 3) a3 = v; else if (q > 3)               a3 = opf4<!CLOS>(a3, v);
    }
    int gx = x0 - P + 4*cg;
    bool okx0 = (unsigned)(gx  ) < WWI, okx1 = (unsigned)(gx+1) < WWI;
    bool okx2 = (unsigned)(gx+2) < WWI, okx3 = (unsigned)(gx+3) < WWI;
    #pragma unroll
    for (int j = 0; j < 4; ++j){
      float4 m = (j==0)?a0:(j==1)?a1:(j==2)?a2:a3;
      int r = R + j;
      bool oky = (unsigned)(y0 - P + r) < HH;
      m.x = (oky && okx0) ? m.x : 0.f;
      m.y = (oky && okx1) ? m.y : 0.f;
      m.z = (oky && okx2) ? m.z : 0.f;
      m.w = (oky && okx3) ? m.w : 0.f;
      *(float4*)&b0[r*N2x + 4*cg] = m;
    }
  }
  __syncthreads();
  // pass5: dwconv KxK, thread = 2 rows x 4 cols, stream K+1 rows once
  const float* wp = wgt + c*K*K;
  const int cg = tid & 7, rg = tid >> 3;     // rg in [0,32)
  const int c0 = 4*cg, r0 = 2*rg;
  float bb = bias[c];
  float a0=bb, a1=bb, a2=bb, a3=bb;          // row r0
  float e0=bb, e1=bb, e2=bb, e3=bb;          // row r0+1
  #pragma unroll
  for (int q = 0; q <= K; ++q){
    float v[4+2*P];
    const float* p = &b0[(r0+q)*N2x + c0];
    #pragma unroll
    for (int t = 0; t < (4+2*P)/4; ++t){
      float4 f = *(const float4*)(p + 4*t);
      v[4*t]=f.x; v[4*t+1]=f.y; v[4*t+2]=f.z; v[4*t+3]=f.w;
    }
    if (q < K){                    // acc row r0: dy = q
      #pragma unroll
      for (int dx = 0; dx < K; ++dx){
        float w = wp[q*K+dx];
        a0 += w*v[dx]; a1 += w*v[dx+1]; a2 += w*v[dx+2]; a3 += w*v[dx+3];
      }
    }
    if (q >= 1){                   // acc row r0+1: dy = q-1
      #pragma unroll
      for (int dx = 0; dx < K; ++dx){
        float w = wp[(q-1)*K+dx];
        e0 += w*v[dx]; e1 += w*v[dx+1]; e2 += w*v[dx+2]; e3 += w*v[dx+3];
      }
    }
  }
  float* op = outF + (size_t)c*HWX;
  *(float4*)&op[(size_t)(y0+r0  )*WWI + x0 + c0] = make_float4(a0,a1,a2,a3);
  *(float4*)&op[(size_t)(y0+r0+1)*WWI + x0 + c0] = make_float4(e0,e1,e2,e3);
  block_reduce_atomic((a0+a1+a2+a3) + (e0+e1+e2+e3),
                      (a0*a0+a1*a1+a2*a2+a3*a3) + (e0*e0+e1*e1+e2*e2+e3*e3),
                      s1+c, s2+c);
}

// -------- stats of d = sgn*(relu(norm(A)) - x); grid-stride x4 ----------
__global__ __launch_bounds__(256) void diff_stats4(const float4* __restrict__ A,
    const float4* __restrict__ x,
    const float* __restrict__ s1i, const float* __restrict__ s2i, float invN,
    float sgn, float* __restrict__ s1, float* __restrict__ s2){
  int c = blockIdx.z;
  float m, r;
  mk_norm(s1i, s2i, c, invN, m, r);
  size_t base = (size_t)c * (HWX/4) + blockIdx.x * 1024 + threadIdx.x;
  float sv = 0.f, sq = 0.f;
  #pragma unroll
  for (int k = 0; k < 4; ++k){
    size_t i = base + k*256;
    float4 f = A[i], xv = x[i];
    float d0 = sgn * (fmaxf((f.x - m) * r, 0.f) - xv.x);
    float d1 = sgn * (fmaxf((f.y - m) * r, 0.f) - xv.y);
    float d2 = sgn * (fmaxf((f.z - m) * r, 0.f) - xv.z);
    float d3 = sgn * (fmaxf((f.w - m) * r, 0.f) - xv.w);
    sv += d0+d1+d2+d3;
    sq += d0*d0+d1*d1+d2*d2+d3*d3;
  }
  block_reduce_atomic(sv, sq, s1 + c, s2 + c);
}

// ======== 3x3 dwconv of norm(d); d recomputed from A,x; row x 4col =======
// R10 EXACT FORM (chunked fully-unrolled staging, TH=32) — verified best.
__global__ __launch_bounds__(256) void conv3_acc(const float* __restrict__ A,
    const float* __restrict__ x,
    const float* __restrict__ s1A, const float* __restrict__ s2A,
    const float* __restrict__ s1D, const float* __restrict__ s2D, float invN,
    float sgn, const float* __restrict__ w3, const float* __restrict__ b3,
    float* __restrict__ comb, int first){
  __shared__ __align__(16) float S[34*36];
  const int c = blockIdx.z;
  const int x0 = blockIdx.x*32, y0 = blockIdx.y*32;
  float mA_, rA_, mD_, rD_;
  mk_norm(s1A, s2A, c, invN, mA_, rA_);
  mk_norm(s1D, s2D, c, invN, mD_, rD_);
  const float mA = rfl(mA_), rA = rfl(rA_), mD = rfl(mD_), rD = rfl(rD_);
  const float* ap = A + (size_t)c*HWX;
  const float* xp = x + (size_t)c*HWX;
  const int tid = threadIdx.x;
  // 34*34 = 1156 = 4*256 + 132 -> 5 chunks, unrolled for load overlap
  #pragma unroll
  for (int k = 0; k < 5; ++k){
    const int i = tid + k*256;
    const bool act = (k < 4) || (tid < 1156 - 1024);
    const int rr = i / 34, cc = i - rr*34;
    const int gy = y0 - 1 + rr, gx = x0 - 1 + cc;
    const bool ok = act && ((unsigned)gy < HH) && ((unsigned)gx < WWI);
    const int ad = min(max(gy,0),HH-1)*WWI + min(max(gx,0),WWI-1);
    float av = act ? ap[ad] : 0.f;
    float xv = act ? xp[ad] : 0.f;
    float dval = sgn * (fmaxf((av - mA) * rA, 0.f) - xv);
    if (act) S[rr*36+cc] = ok ? (dval - mD) * rD : 0.f;
  }
  __syncthreads();
  const int cg = tid & 7, row = tid >> 3;
  const int c0 = 4*cg;
  const float* wp = w3 + c*9;
  float bb = b3[c];
  float acc[4] = {bb,bb,bb,bb};
  #pragma unroll
  for (int dy = 0; dy < 3; ++dy){
    const float* p = &S[(row+dy)*36 + c0];
    float4 t0 = *(const float4*)p;
    float4 t1 = *(const float4*)(p+4);
    float v[6] = {t0.x,t0.y,t0.z,t0.w,t1.x,t1.y};
    #pragma unroll
    for (int dx = 0; dx < 3; ++dx){
      float w = wp[dy*3+dx];
      #pragma unroll
      for (int j = 0; j < 4; ++j) acc[j] += w * v[j+dx];
    }
  }
  float4* cp = (float4*)&comb[(size_t)c*HWX + (y0+row)*WWI + x0 + c0];
  float4 o = make_float4(acc[0],acc[1],acc[2],acc[3]);
  if (!first){
    float4 prev = *cp;
    o.x += prev.x; o.y += prev.y; o.z += prev.z; o.w += prev.w;
  }
  *cp = o;
}

// ======== Conv3d #1: 4 d-planes per block, 6 staged planes, row x 4col ====
// Staging: chunk-outer / plane-inner (R10 proven form).
__global__ __launch_bounds__(256) void conv3d1(const float* __restrict__ comb,
    const float* __restrict__ wt, const float* __restrict__ bt,
    bf16* __restrict__ T, float* __restrict__ s1, float* __restrict__ s2){
  __shared__ __align__(16) float S[6][34*36];
  __shared__ float red[4][6];
  const int d0 = blockIdx.z * 4;
  const int x0 = blockIdx.x*32, y0 = blockIdx.y*32;
  const int tid = threadIdx.x;
  #pragma unroll
  for (int k = 0; k < 5; ++k){
    const int i = tid + k*256;
    const bool act = (k < 4) || (tid < 1156 - 1024);
    const int rr = i / 34, cc = i - rr*34;
    const int gy = y0 - 1 + rr, gx = x0 - 1 + cc;
    const bool okxy = act && ((unsigned)gy < HH) && ((unsigned)gx < WWI);
    const int ad = min(max(gy,0),HH-1)*WWI + min(max(gx,0),WWI-1);
    float v[6];
    #pragma unroll
    for (int j = 0; j < 6; ++j){
      const int dz = d0 - 1 + j;
      const float* ip = comb + (size_t)min(max(dz,0),CC-1) * HWX;
      v[j] = act ? ip[ad] : 0.f;
    }
    #pragma unroll
    for (int j = 0; j < 6; ++j){
      const bool ok = okxy && ((unsigned)(d0-1+j) < CC);
      if (act) S[j][rr*36+cc] = ok ? v[j] : 0.f;
    }
  }
  __syncthreads();
  const int cg = tid & 7, row = tid >> 3;
  const int c0 = 4*cg;
  const int lane = tid & 63, wid = tid >> 6;
  for (int dl = 0; dl < 4; ++dl){
    const int d = d0 + dl;
    float acc[3][4];
    #pragma unroll
    for (int oc = 0; oc < 3; ++oc){
      float b = bt[oc];
      #pragma unroll
      for (int j = 0; j < 4; ++j) acc[oc][j] = b;
    }
    #pragma unroll
    for (int dd = 0; dd < 3; ++dd){
      const float* sp = S[dl+dd];
      #pragma unroll
      for (int dy = 0; dy < 3; ++dy){
        const float* p = &sp[(row+dy)*36 + c0];
        float4 t0 = *(const float4*)p;
        float4 t1 = *(const float4*)(p+4);
        float v[6] = {t0.x,t0.y,t0.z,t0.w,t1.x,t1.y};
        #pragma unroll
        for (int dx = 0; dx < 3; ++dx){
          #pragma unroll
          for (int oc = 0; oc < 3; ++oc){
            float w = wt[oc*27 + dd*9 + dy*3 + dx];
            #pragma unroll
            for (int j = 0; j < 4; ++j) acc[oc][j] += w * v[j+dx];
          }
        }
      }
    }
    float vals[6] = {0,0,0,0,0,0};
    #pragma unroll
    for (int oc = 0; oc < 3; ++oc){
      bf16* tp = T + (size_t)(oc*CC + d)*HWX;
      union { ushort4 u; bf16 h[4]; } pk;
      #pragma unroll
      for (int j = 0; j < 4; ++j){
        pk.h[j] = f2b(acc[oc][j]);
        float av = b2f(pk.h[j]);          // stats match stored bf16
        vals[2*oc]   += av;
        vals[2*oc+1] += av*av;
      }
      *(ushort4*)&tp[(size_t)(y0+row)*WWI + x0 + c0] = pk.u;
    }
    #pragma unroll
    for (int o = 32; o > 0; o >>= 1)
      #pragma unroll
      for (int k = 0; k < 6; ++k) vals[k] += __shfl_down(vals[k], o);
    __syncthreads();                      // protect red[] from prev iter
    if (lane == 0)
      #pragma unroll
      for (int k = 0; k < 6; ++k) red[wid][k] = vals[k];
    __syncthreads();
    if (tid == 0){
      #pragma unroll
      for (int oc = 0; oc < 3; ++oc){
        atomicAdd(s1 + oc*CC + d, red[0][2*oc]  +red[1][2*oc]  +red[2][2*oc]  +red[3][2*oc]);
        atomicAdd(s2 + oc*CC + d, red[0][2*oc+1]+red[1][2*oc+1]+red[2][2*oc+1]+red[3][2*oc+1]);
      }
    }
  }
}

// ======== Conv3d #2: DPB=2, 12 relu-norm bf16 planes, pitch 36 ==========
// R10 PROVEN FORM (VGPR 44, occ 54%). Four restructure attempts all
// regressed on VGPR/occupancy/L2 cliffs — measured optimum.
__global__ __launch_bounds__(256) void conv3d2_final(const bf16* __restrict__ T,
    const float* __restrict__ s1i, const float* __restrict__ s2i, float invN,
    const float* __restrict__ wt2, const float* __restrict__ bt2,
    const float* __restrict__ x, float* __restrict__ out){
  __shared__ __align__(16) bf16 S16[12][34*36];   // 29376 B
  const int d0 = blockIdx.z * 2;
  const int x0 = blockIdx.x*32, y0 = blockIdx.y*32;
  const int tid = threadIdx.x;

  // uniform per-plane params (SGPR-pinned)
  float ms[12], rs[12];
  #pragma unroll
  for (int p = 0; p < 12; ++p){
    const int i3 = p >> 2, j = p & 3;
    const int dz = d0 - 1 + j;
    const int ch = i3*CC + min(max(dz,0),CC-1);
    float m, r; mk_norm(s1i, s2i, ch, invN, m, r);
    ms[p] = rfl(m); rs[p] = rfl(r);
  }

  // stage 12 planes in 3 chunks of 12 independent loads (34 x 18 pairs)
  #pragma unroll
  for (int k = 0; k < 3; ++k){
    const int i = tid + k*256;              // index in 34x18 element grid
    const bool act = (k < 2) || (tid < 612 - 512);
    const int rr = i / 18, s = i - rr*18;
    const int gy = y0 - 1 + rr;
    const int gx = x0 - 2 + 2*s;            // even, cols 0..35
    const int ay = min(max(gy,0),HH-1);
    const int ax = min(max(gx,0),WWI-2);    // even, ushort2-safe
    const int aoff = (ay<<9) + ax;
    unsigned int tv[12];
    #pragma unroll
    for (int p = 0; p < 12; ++p){
      const int i3 = p >> 2, j = p & 3;
      const int ch = i3*CC + min(max(d0-1+j,0),CC-1);
      const bf16* tp = T + (size_t)ch*HWX;
      ushort2 t = act ? *(const ushort2*)(tp + aoff) : make_ushort2(0,0);
      tv[p] = (((unsigned)t.y) << 16) | (unsigned)t.x;
    }
    const bool oky  = act && ((unsigned)gy < HH);
    const bool okx0 = (unsigned)gx     < WWI;
    const bool okx1 = (unsigned)(gx+1) < WWI;
    #pragma unroll
    for (int p = 0; p < 12; ++p){
      const int j = p & 3;
      const bool zok = (unsigned)(d0-1+j) < CC;
      const bool bok = oky && zok;
      unsigned lo = tv[p] << 16, hi = tv[p] & 0xffff0000u;
      float f0, f1;
      __builtin_memcpy(&f0, &lo, 4); __builtin_memcpy(&f1, &hi, 4);
      float u0 = (bok && okx0) ? fmaxf((f0 - ms[p]) * rs[p], 0.f) : 0.f;
      float u1 = (bok && okx1) ? fmaxf((f1 - ms[p]) * rs[p], 0.f) : 0.f;
      union { ushort2 u; bf16 h[2]; } pk;
      pk.h[0] = f2b(u0); pk.h[1] = f2b(u1);
      if (act) *(ushort2*)(S16[p] + rr*36 + 2*s) = pk.u;
    }
  }
  __syncthreads();

  const int cg = tid & 7, row = tid >> 3;
  const int c0 = 4*cg;
  for (int dl = 0; dl < 2; ++dl){
    const int d = d0 + dl;
    const float bb = bt2[0];
    float acc[4] = {bb,bb,bb,bb};
    #pragma unroll
    for (int i3 = 0; i3 < 3; ++i3){
      #pragma unroll
      for (int dd = 0; dd < 3; ++dd){
        const bf16* sp = S16[i3*4 + dl + dd];
        #pragma unroll
        for (int dy = 0; dy < 3; ++dy){
          // needed cols (global x0+c0-1 .. x0+c0+4) = LDS cols c0+1 .. c0+6
          const bf16* p = &sp[(row+dy)*36 + c0];
          ushort4 lo = *(const ushort4*)p;
          ushort4 hi = *(const ushort4*)(p+4);
          float v[6] = {u2f(lo.y),u2f(lo.z),u2f(lo.w),
                        u2f(hi.x),u2f(hi.y),u2f(hi.z)};
          #pragma unroll
          for (int dx = 0; dx < 3; ++dx){
            float w = wt2[(i3*3+dd)*9 + dy*3 + dx];
            #pragma unroll
            for (int q = 0; q < 4; ++q) acc[q] += w * v[q+dx];
          }
        }
      }
    }
    size_t gi = (size_t)d*HWX + (size_t)(y0+row)*WWI + x0 + c0;
    float4 xv = *(const float4*)&x[gi];
    float4 o;
    o.x = fmaxf(xv.x / (1.f + __expf(-acc[0])), 0.f);
    o.y = fmaxf(xv.y / (1.f + __expf(-acc[1])), 0.f);
    o.z = fmaxf(xv.z / (1.f + __expf(-acc[2])), 0.f);
    o.w = fmaxf(xv.w / (1.f + __expf(-acc[3])), 0.f);
    *(float4*)&out[gi] = o;
  }
}

extern "C" void kernel_launch(void* const* d_in, const int* in_sizes, int n_in,
                              void* d_out, int out_size, void* d_ws, size_t ws_size,
                              hipStream_t stream){
  const float* x     = (const float*)d_in[0];
  const float* w_wt5 = (const float*)d_in[1];
  const float* b_wt5 = (const float*)d_in[2];
  const float* w_wt9 = (const float*)d_in[3];
  const float* b_wt9 = (const float*)d_in[4];
  const float* w_bt5 = (const float*)d_in[5];
  const float* b_bt5 = (const float*)d_in[6];
  const float* w_bt9 = (const float*)d_in[7];
  const float* b_bt9 = (const float*)d_in[8];
  const float* w_wn  = (const float*)d_in[9];
  const float* b_wn  = (const float*)d_in[10];
  const float* w_t1  = (const float*)d_in[11];
  const float* b_t1  = (const float*)d_in[12];
  const float* w_t2  = (const float*)d_in[13];
  const float* b_t2  = (const float*)d_in[14];
  float* out = (float*)d_out;

  // ---- workspace layout ----
  char* ws = (char*)d_ws;
  float* A    = (float*)ws;                        // branch dwconv out
  float* comb = (float*)(ws + 2*(size_t)CHWX*4);   // accumulator
  bf16*  T    = (bf16*)ws;                         // 3*CHWX bf16 overlay
  float* stats = comb + (size_t)CHWX;
  float* s1 = stats;        // 704
  float* s2 = stats + 704;  // 704

  hipMemsetAsync(s1, 0, 1408 * sizeof(float), stream);

  dim3 blk(256);
  dim3 gridMor(WWI/32, HH/64, CC);          // (16,8,64) morphdw 32x64 tile
  dim3 gridC3(WWI/32, HH/32, CC);           // (16,16,64) conv3_acc 32x32 tile
  dim3 gridM4(WWI/32, HH/32, CC/4);         // (16,16,16)
  dim3 gridT2(WWI/32, HH/32, CC/2);         // (16,16,32) conv3d2 DPB=2
  dim3 gridD(64, 1, CC);                    // diff grid-stride x4
  float invHW = 1.f / (float)HWX;

  int first = 1;
  for (int ki = 0; ki < 2; ++ki){
    for (int br = 0; br < 2; ++br){
      int st = (ki * 2 + br) * 2;
      if (ki == 0){
        if (br == 0) morphdw<2, true ><<<gridMor, blk, 0, stream>>>(x, w_wt5, b_wt5, A, s1+st*64, s2+st*64);
        else         morphdw<2, false><<<gridMor, blk, 0, stream>>>(x, w_bt5, b_bt5, A, s1+st*64, s2+st*64);
      } else {
        if (br == 0) morphdw<4, true ><<<gridMor, blk, 0, stream>>>(x, w_wt9, b_wt9, A, s1+st*64, s2+st*64);
        else         morphdw<4, false><<<gridMor, blk, 0, stream>>>(x, w_bt9, b_bt9, A, s1+st*64, s2+st*64);
      }
      float sgn = (br == 0) ? -1.f : 1.f;   // WTHAM: x - wth ; BTHAM: bth - x
      diff_stats4<<<gridD, blk, 0, stream>>>((const float4*)A, (const float4*)x,
                                             s1 + st*64, s2 + st*64, invHW, sgn,
                                             s1 + (st+1)*64, s2 + (st+1)*64);
      conv3_acc<<<gridC3, blk, 0, stream>>>(A, x, s1 + st*64, s2 + st*64,
                                            s1 + (st+1)*64, s2 + (st+1)*64, invHW,
                                            sgn, w_wn, b_wn, comb, first);
      first = 0;
    }
  }

  // ---- temporal cross ----
  conv3d1<<<gridM4, blk, 0, stream>>>(comb, w_t1, b_t1, T, s1 + 512, s2 + 512);
  conv3d2_final<<<gridT2, blk, 0, stream>>>(T, s1 + 512, s2 + 512, invHW,
                                            w_t2, b_t2, x, out);
}